// Round 1
// baseline (1206.662 us; speedup 1.0000x reference)
//
#include <hip/hip_runtime.h>
#include <hip/hip_bf16.h>

#define N_NODES 100000
#define N_EDGES 800000
#define NEG 0.2f
#define BN_EPS 1e-5f
#define G_BN 240

// ---------------- CSR build (dst-sorted edge list) ----------------
__global__ void k_hist(const int* __restrict__ dst, int* __restrict__ cnt, int e) {
  int i = blockIdx.x * blockDim.x + threadIdx.x;
  if (i < e) atomicAdd(&cnt[dst[i]], 1);
}

__global__ void k_scan1(const int* __restrict__ cnt, int* __restrict__ rowptr,
                        int* __restrict__ bsums, int n) {
  __shared__ int sm[256];
  int i = blockIdx.x * 256 + threadIdx.x;
  int v = (i < n) ? cnt[i] : 0;
  sm[threadIdx.x] = v;
  __syncthreads();
  for (int off = 1; off < 256; off <<= 1) {
    int t = (threadIdx.x >= off) ? sm[threadIdx.x - off] : 0;
    __syncthreads();
    sm[threadIdx.x] += t;
    __syncthreads();
  }
  if (i < n) rowptr[i + 1] = sm[threadIdx.x];
  if (threadIdx.x == 255) bsums[blockIdx.x] = sm[255];
}

__global__ void k_scan2(int* __restrict__ bsums, int nb) {
  __shared__ int sm[512];
  int v = (threadIdx.x < nb) ? bsums[threadIdx.x] : 0;
  sm[threadIdx.x] = v;
  __syncthreads();
  for (int off = 1; off < 512; off <<= 1) {
    int t = (threadIdx.x >= off) ? sm[threadIdx.x - off] : 0;
    __syncthreads();
    sm[threadIdx.x] += t;
    __syncthreads();
  }
  if (threadIdx.x < nb) bsums[threadIdx.x] = sm[threadIdx.x] - v;  // exclusive
}

__global__ void k_scan3(int* __restrict__ rowptr, const int* __restrict__ bsums,
                        int* __restrict__ cursor, int n) {
  int i = blockIdx.x * 256 + threadIdx.x;
  if (i < n) {
    int val = rowptr[i + 1] + bsums[blockIdx.x];
    rowptr[i + 1] = val;
    if (i + 1 < n) cursor[i + 1] = val;
  }
  if (i == 0) { rowptr[0] = 0; cursor[0] = 0; }
}

__global__ void k_scatter(const int* __restrict__ src, const int* __restrict__ dst,
                          int* __restrict__ cursor, int* __restrict__ ssort, int e) {
  int i = blockIdx.x * blockDim.x + threadIdx.x;
  if (i < e) {
    int pos = atomicAdd(&cursor[dst[i]], 1);
    ssort[pos] = src[i];
  }
}

// ---------------- 128-col GEMM: C = act(A @ W) ----------------
// FLAGS bit0: epilogue +bias, relu (encoder). FLAGS bit1: prologue BN+relu on A.
template <int FLAGS>
__global__ __launch_bounds__(256) void k_gemm128(
    const float* __restrict__ A, const float* __restrict__ W,
    const float* __restrict__ bias, const float* __restrict__ stats,
    float* __restrict__ C, int n) {
  __shared__ float Wl[128 * 128];
  __shared__ float Xl[8 * 132];
  for (int i = threadIdx.x * 4; i < 128 * 128; i += 1024)
    *(float4*)&Wl[i] = *(const float4*)&W[i];
  int cg = threadIdx.x & 31;   // cols 4cg..4cg+3
  int rg = threadIdx.x >> 5;   // row 0..7
  float4 bv = make_float4(0.f, 0.f, 0.f, 0.f);
  if (FLAGS & 1) bv = *(const float4*)&bias[4 * cg];
  for (int rb = blockIdx.x * 8; rb < n; rb += gridDim.x * 8) {
    __syncthreads();
    {
      int idx = threadIdx.x * 4;
      int r = idx >> 7, c = idx & 127;
      float4 v = *(const float4*)&A[(size_t)(rb + r) * 128 + c];
      if (FLAGS & 2) {
        float4 sc = *(const float4*)&stats[c];
        float4 sh = *(const float4*)&stats[128 + c];
        v.x = fmaxf(v.x * sc.x + sh.x, 0.f);
        v.y = fmaxf(v.y * sc.y + sh.y, 0.f);
        v.z = fmaxf(v.z * sc.z + sh.z, 0.f);
        v.w = fmaxf(v.w * sc.w + sh.w, 0.f);
      }
      *(float4*)&Xl[r * 132 + c] = v;
    }
    __syncthreads();
    float a0 = 0.f, a1 = 0.f, a2 = 0.f, a3 = 0.f;
#pragma unroll 4
    for (int k = 0; k < 128; ++k) {
      float x = Xl[rg * 132 + k];
      float4 w = *(float4*)&Wl[k * 128 + 4 * cg];
      a0 += x * w.x; a1 += x * w.y; a2 += x * w.z; a3 += x * w.w;
    }
    float4 o = make_float4(a0, a1, a2, a3);
    if (FLAGS & 1) {
      o.x = fmaxf(o.x + bv.x, 0.f);
      o.y = fmaxf(o.y + bv.y, 0.f);
      o.z = fmaxf(o.z + bv.z, 0.f);
      o.w = fmaxf(o.w + bv.w, 0.f);
    }
    *(float4*)&C[(size_t)(rb + rg) * 128 + 4 * cg] = o;
  }
}

// ---------------- predictor: out = bnrelu(A) @ Wp + bp (40 cols) ----------------
__global__ __launch_bounds__(320) void k_pred(
    const float* __restrict__ A, const float* __restrict__ stats,
    const float* __restrict__ W, const float* __restrict__ bias,
    float* __restrict__ out, int n) {
  __shared__ float Wl[128 * 40];
  __shared__ float Xl[32 * 132];
  for (int i = threadIdx.x; i < 128 * 40; i += 320) Wl[i] = W[i];
  int cg = threadIdx.x % 10;  // cols 4cg..4cg+3
  int rg = threadIdx.x / 10;  // row 0..31
  float4 bv = *(const float4*)&bias[4 * cg];
  for (int rb = blockIdx.x * 32; rb < n; rb += gridDim.x * 32) {
    __syncthreads();
    for (int idx = threadIdx.x; idx < 1024; idx += 320) {
      int r = idx >> 5, c = (idx & 31) * 4;
      float4 v = *(const float4*)&A[(size_t)(rb + r) * 128 + c];
      float4 sc = *(const float4*)&stats[c];
      float4 sh = *(const float4*)&stats[128 + c];
      v.x = fmaxf(v.x * sc.x + sh.x, 0.f);
      v.y = fmaxf(v.y * sc.y + sh.y, 0.f);
      v.z = fmaxf(v.z * sc.z + sh.z, 0.f);
      v.w = fmaxf(v.w * sc.w + sh.w, 0.f);
      *(float4*)&Xl[r * 132 + c] = v;
    }
    __syncthreads();
    float a0 = 0.f, a1 = 0.f, a2 = 0.f, a3 = 0.f;
#pragma unroll 4
    for (int k = 0; k < 128; ++k) {
      float x = Xl[rg * 132 + k];
      float4 w = *(float4*)&Wl[k * 40 + 4 * cg];
      a0 += x * w.x; a1 += x * w.y; a2 += x * w.z; a3 += x * w.w;
    }
    float4 o = make_float4(a0 + bv.x, a1 + bv.y, a2 + bv.z, a3 + bv.w);
    *(float4*)&out[(size_t)(rb + rg) * 40 + 4 * cg] = o;
  }
}

// ---------------- per-node attention coefficients el/er ----------------
__global__ __launch_bounds__(256) void k_edgecoef(
    const float* __restrict__ hf, const float* __restrict__ al,
    const float* __restrict__ ar, float* __restrict__ el,
    float* __restrict__ er, int n) {
  int gid = blockIdx.x * 256 + threadIdx.x;
  int wid = gid >> 6, lane = gid & 63;
  if (wid >= n) return;
  float2 hv = *(const float2*)(hf + (size_t)wid * 128 + 2 * lane);
  float2 avl = *(const float2*)(al + 2 * lane);
  float2 avr = *(const float2*)(ar + 2 * lane);
  float pl = hv.x * avl.x + hv.y * avl.y;
  float pr = hv.x * avr.x + hv.y * avr.y;
  for (int off = 1; off < 16; off <<= 1) {
    pl += __shfl_xor(pl, off);
    pr += __shfl_xor(pr, off);
  }
  if ((lane & 15) == 0) {
    int h = lane >> 4;
    el[wid * 4 + h] = pl;
    er[wid * 4 + h] = pr;
  }
}

// ---------------- per-node online-softmax aggregation (1 wave/node) ----------------
__global__ __launch_bounds__(256) void k_aggregate(
    const float* __restrict__ hf, const float* __restrict__ el,
    const float* __restrict__ er, const int* __restrict__ rowptr,
    const int* __restrict__ ssort, const float* __restrict__ bias,
    float* __restrict__ hpre, int n, int addres) {
  int gid = blockIdx.x * 256 + threadIdx.x;
  int wid = gid >> 6, lane = gid & 63;
  if (wid >= n) return;
  int beg = rowptr[wid], end = rowptr[wid + 1];
  float4 erv = *(const float4*)(er + 4 * wid);
  float m0 = -1e30f, m1 = -1e30f, m2 = -1e30f, m3 = -1e30f;
  float s0 = 0.f, s1 = 0.f, s2 = 0.f, s3 = 0.f;
  float a0 = 0.f, a1 = 0.f;
  int h = lane >> 4;
  int c0 = 2 * lane;
  for (int j = beg; j < end; ++j) {
    int sidx = ssort[j];
    float4 ev = *(const float4*)(el + 4 * sidx);
    float2 hv = *(const float2*)(hf + (size_t)sidx * 128 + c0);
    float e0 = ev.x + erv.x; e0 = (e0 > 0.f) ? e0 : NEG * e0;
    float e1 = ev.y + erv.y; e1 = (e1 > 0.f) ? e1 : NEG * e1;
    float e2 = ev.z + erv.z; e2 = (e2 > 0.f) ? e2 : NEG * e2;
    float e3 = ev.w + erv.w; e3 = (e3 > 0.f) ? e3 : NEG * e3;
    float n0 = fmaxf(m0, e0), n1 = fmaxf(m1, e1);
    float n2 = fmaxf(m2, e2), n3 = fmaxf(m3, e3);
    float sc0 = __expf(m0 - n0), sc1 = __expf(m1 - n1);
    float sc2 = __expf(m2 - n2), sc3 = __expf(m3 - n3);
    float w0 = __expf(e0 - n0), w1 = __expf(e1 - n1);
    float w2 = __expf(e2 - n2), w3 = __expf(e3 - n3);
    s0 = s0 * sc0 + w0; s1 = s1 * sc1 + w1;
    s2 = s2 * sc2 + w2; s3 = s3 * sc3 + w3;
    m0 = n0; m1 = n1; m2 = n2; m3 = n3;
    float sc = (h < 2) ? (h == 0 ? sc0 : sc1) : (h == 2 ? sc2 : sc3);
    float w  = (h < 2) ? (h == 0 ? w0  : w1)  : (h == 2 ? w2  : w3);
    a0 = a0 * sc + w * hv.x;
    a1 = a1 * sc + w * hv.y;
  }
  float s = (h < 2) ? (h == 0 ? s0 : s1) : (h == 2 ? s2 : s3);
  float inv = (end > beg) ? 1.f / s : 0.f;
  float2 res = make_float2(0.f, 0.f);
  if (addres) res = *(const float2*)(hpre + (size_t)wid * 128 + c0);
  float o0 = a0 * inv + bias[c0] + res.x;
  float o1 = a1 * inv + bias[c0 + 1] + res.y;
  *(float2*)(hpre + (size_t)wid * 128 + c0) = make_float2(o0, o1);
}

// ---------------- batchnorm stats ----------------
__global__ __launch_bounds__(256) void k_bnpart(const float* __restrict__ x,
                                                float* __restrict__ part, int n) {
  int c = threadIdx.x & 127;
  int half = threadIdx.x >> 7;
  float s = 0.f, q = 0.f;
  for (int r = blockIdx.x * 2 + half; r < n; r += gridDim.x * 2) {
    float v = x[(size_t)r * 128 + c];
    s += v; q += v * v;
  }
  __shared__ float sm[512];
  sm[threadIdx.x] = s; sm[256 + threadIdx.x] = q;
  __syncthreads();
  if (threadIdx.x < 128) {
    part[blockIdx.x * 256 + threadIdx.x] = sm[threadIdx.x] + sm[threadIdx.x + 128];
    part[blockIdx.x * 256 + 128 + threadIdx.x] =
        sm[256 + threadIdx.x] + sm[256 + threadIdx.x + 128];
  }
}

__global__ void k_bnfin(const float* __restrict__ part, const float* __restrict__ gamma,
                        const float* __restrict__ beta, float* __restrict__ stats,
                        int g, int n) {
  int c = threadIdx.x;  // 128 threads
  float s = 0.f, q = 0.f;
  for (int b = 0; b < g; ++b) {
    s += part[b * 256 + c];
    q += part[b * 256 + 128 + c];
  }
  float mean = s / n;
  float var = q / n - mean * mean;
  float rstd = rsqrtf(var + BN_EPS);
  float scale = gamma[c] * rstd;
  stats[c] = scale;
  stats[128 + c] = beta[c] - mean * scale;
}

extern "C" void kernel_launch(void* const* d_in, const int* in_sizes, int n_in,
                              void* d_out, int out_size, void* d_ws, size_t ws_size,
                              hipStream_t stream) {
  const float* feat   = (const float*)d_in[0];
  const int*   src    = (const int*)d_in[1];
  const int*   dst    = (const int*)d_in[2];
  const float* W_enc  = (const float*)d_in[3];
  const float* b_enc  = (const float*)d_in[4];
  const float* Ws     = (const float*)d_in[5];
  const float* a_ls   = (const float*)d_in[6];
  const float* a_rs   = (const float*)d_in[7];
  const float* biases = (const float*)d_in[8];
  const float* gammas = (const float*)d_in[9];
  const float* betas  = (const float*)d_in[10];
  const float* W_pred = (const float*)d_in[11];
  const float* b_pred = (const float*)d_in[12];
  float* out = (float*)d_out;

  char* p = (char*)d_ws;
  float* h    = (float*)p; p += (size_t)N_NODES * 128 * 4;
  float* hf   = (float*)p; p += (size_t)N_NODES * 128 * 4;
  float* hpre = (float*)p; p += (size_t)N_NODES * 128 * 4;
  float* el   = (float*)p; p += (size_t)N_NODES * 4 * 4;
  float* er   = (float*)p; p += (size_t)N_NODES * 4 * 4;
  float* part = (float*)p; p += (size_t)G_BN * 256 * 4;
  float* stats= (float*)p; p += 256 * 4;
  int* rowptr = (int*)p;   p += (size_t)(N_NODES + 1) * 4;
  int* cursor = (int*)p;   p += (size_t)N_NODES * 4;
  int* bsums  = (int*)p;   p += 512 * 4;
  int* ssort  = (int*)p;   p += (size_t)N_EDGES * 4;

  // CSR build (dst-sorted)
  hipMemsetAsync(cursor, 0, (size_t)N_NODES * 4, stream);
  k_hist<<<(N_EDGES + 255) / 256, 256, 0, stream>>>(dst, cursor, N_EDGES);
  int nb = (N_NODES + 255) / 256;  // 391
  k_scan1<<<nb, 256, 0, stream>>>(cursor, rowptr, bsums, N_NODES);
  k_scan2<<<1, 512, 0, stream>>>(bsums, nb);
  k_scan3<<<nb, 256, 0, stream>>>(rowptr, bsums, cursor, N_NODES);
  k_scatter<<<(N_EDGES + 255) / 256, 256, 0, stream>>>(src, dst, cursor, ssort, N_EDGES);

  // encoder: h = relu(feat @ W_enc + b_enc)
  k_gemm128<1><<<1024, 256, 0, stream>>>(feat, W_enc, b_enc, nullptr, h, N_NODES);

  int aggblocks = (N_NODES * 64 + 255) / 256;  // 25000
  for (int L = 0; L < 3; ++L) {
    if (L == 0)
      k_gemm128<0><<<1024, 256, 0, stream>>>(h, Ws + (size_t)L * 16384, nullptr, nullptr,
                                             hf, N_NODES);
    else
      k_gemm128<2><<<1024, 256, 0, stream>>>(hpre, Ws + (size_t)L * 16384, nullptr, stats,
                                             hf, N_NODES);
    k_edgecoef<<<aggblocks, 256, 0, stream>>>(hf, a_ls + L * 128, a_rs + L * 128, el, er,
                                              N_NODES);
    k_aggregate<<<aggblocks, 256, 0, stream>>>(hf, el, er, rowptr, ssort,
                                               biases + L * 128, hpre, N_NODES,
                                               L > 0 ? 1 : 0);
    k_bnpart<<<G_BN, 256, 0, stream>>>(hpre, part, N_NODES);
    k_bnfin<<<1, 128, 0, stream>>>(part, gammas + L * 128, betas + L * 128, stats, G_BN,
                                   N_NODES);
  }
  // predictor uses layer-2 BN stats
  k_pred<<<512, 320, 0, stream>>>(hpre, stats, W_pred, b_pred, out, N_NODES);
}

// Round 2
// 1153.463 us; speedup vs baseline: 1.0461x; 1.0461x over previous
//
#include <hip/hip_runtime.h>
#include <hip/hip_bf16.h>

#define N_NODES 100000
#define N_EDGES 800000
#define NEG 0.2f
#define BN_EPS 1e-5f
#define G_BN 240

// ---------------- CSR build (dst-sorted edge list) ----------------
__global__ void k_hist(const int* __restrict__ dst, int* __restrict__ cnt, int e) {
  int i = blockIdx.x * blockDim.x + threadIdx.x;
  if (i < e) atomicAdd(&cnt[dst[i]], 1);
}

__global__ void k_scan1(const int* __restrict__ cnt, int* __restrict__ rowptr,
                        int* __restrict__ bsums, int n) {
  __shared__ int sm[256];
  int i = blockIdx.x * 256 + threadIdx.x;
  int v = (i < n) ? cnt[i] : 0;
  sm[threadIdx.x] = v;
  __syncthreads();
  for (int off = 1; off < 256; off <<= 1) {
    int t = (threadIdx.x >= off) ? sm[threadIdx.x - off] : 0;
    __syncthreads();
    sm[threadIdx.x] += t;
    __syncthreads();
  }
  if (i < n) rowptr[i + 1] = sm[threadIdx.x];
  if (threadIdx.x == 255) bsums[blockIdx.x] = sm[255];
}

__global__ void k_scan2(int* __restrict__ bsums, int nb) {
  __shared__ int sm[512];
  int v = (threadIdx.x < nb) ? bsums[threadIdx.x] : 0;
  sm[threadIdx.x] = v;
  __syncthreads();
  for (int off = 1; off < 512; off <<= 1) {
    int t = (threadIdx.x >= off) ? sm[threadIdx.x - off] : 0;
    __syncthreads();
    sm[threadIdx.x] += t;
    __syncthreads();
  }
  if (threadIdx.x < nb) bsums[threadIdx.x] = sm[threadIdx.x] - v;  // exclusive
}

__global__ void k_scan3(int* __restrict__ rowptr, const int* __restrict__ bsums,
                        int* __restrict__ cursor, int n) {
  int i = blockIdx.x * 256 + threadIdx.x;
  if (i < n) {
    int val = rowptr[i + 1] + bsums[blockIdx.x];
    rowptr[i + 1] = val;
    if (i + 1 < n) cursor[i + 1] = val;
  }
  if (i == 0) { rowptr[0] = 0; cursor[0] = 0; }
}

__global__ void k_scatter(const int* __restrict__ src, const int* __restrict__ dst,
                          int* __restrict__ cursor, int* __restrict__ ssort, int e) {
  int i = blockIdx.x * blockDim.x + threadIdx.x;
  if (i < e) {
    int pos = atomicAdd(&cursor[dst[i]], 1);
    ssort[pos] = src[i];
  }
}

// ---------------- 128-col GEMM: C = act(A @ W) ----------------
// FLAGS bit0: epilogue +bias, relu (encoder). FLAGS bit1: prologue BN+relu on A.
// FLAGS bit2: compute el/er = (C @ a_l), (C @ a_r) per head in epilogue.
template <int FLAGS>
__global__ __launch_bounds__(256) void k_gemm128(
    const float* __restrict__ A, const float* __restrict__ W,
    const float* __restrict__ bias, const float* __restrict__ stats,
    const float* __restrict__ al, const float* __restrict__ ar,
    float* __restrict__ el, float* __restrict__ er,
    float* __restrict__ C, int n) {
  __shared__ float Wl[128 * 128];
  __shared__ float Xl[8 * 132];
  for (int i = threadIdx.x * 4; i < 128 * 128; i += 1024)
    *(float4*)&Wl[i] = *(const float4*)&W[i];
  int cg = threadIdx.x & 31;   // cols 4cg..4cg+3
  int rg = threadIdx.x >> 5;   // row 0..7
  float4 bv = make_float4(0.f, 0.f, 0.f, 0.f);
  if (FLAGS & 1) bv = *(const float4*)&bias[4 * cg];
  float4 alv = make_float4(0.f, 0.f, 0.f, 0.f);
  float4 arv = make_float4(0.f, 0.f, 0.f, 0.f);
  if (FLAGS & 4) {
    alv = *(const float4*)&al[4 * cg];
    arv = *(const float4*)&ar[4 * cg];
  }
  for (int rb = blockIdx.x * 8; rb < n; rb += gridDim.x * 8) {
    __syncthreads();
    {
      int idx = threadIdx.x * 4;
      int r = idx >> 7, c = idx & 127;
      float4 v = *(const float4*)&A[(size_t)(rb + r) * 128 + c];
      if (FLAGS & 2) {
        float4 sc = *(const float4*)&stats[c];
        float4 sh = *(const float4*)&stats[128 + c];
        v.x = fmaxf(v.x * sc.x + sh.x, 0.f);
        v.y = fmaxf(v.y * sc.y + sh.y, 0.f);
        v.z = fmaxf(v.z * sc.z + sh.z, 0.f);
        v.w = fmaxf(v.w * sc.w + sh.w, 0.f);
      }
      *(float4*)&Xl[r * 132 + c] = v;
    }
    __syncthreads();
    float a0 = 0.f, a1 = 0.f, a2 = 0.f, a3 = 0.f;
#pragma unroll 4
    for (int k = 0; k < 128; ++k) {
      float x = Xl[rg * 132 + k];
      float4 w = *(float4*)&Wl[k * 128 + 4 * cg];
      a0 += x * w.x; a1 += x * w.y; a2 += x * w.z; a3 += x * w.w;
    }
    float4 o = make_float4(a0, a1, a2, a3);
    if (FLAGS & 1) {
      o.x = fmaxf(o.x + bv.x, 0.f);
      o.y = fmaxf(o.y + bv.y, 0.f);
      o.z = fmaxf(o.z + bv.z, 0.f);
      o.w = fmaxf(o.w + bv.w, 0.f);
    }
    if (FLAGS & 4) {
      // per-head attention coefficients from this row's outputs
      float pl = o.x * alv.x + o.y * alv.y + o.z * alv.z + o.w * alv.w;
      float pr = o.x * arv.x + o.y * arv.y + o.z * arv.z + o.w * arv.w;
      pl += __shfl_xor(pl, 1); pr += __shfl_xor(pr, 1);
      pl += __shfl_xor(pl, 2); pr += __shfl_xor(pr, 2);
      pl += __shfl_xor(pl, 4); pr += __shfl_xor(pr, 4);
      if ((cg & 7) == 0) {
        int h = cg >> 3;
        el[(size_t)(rb + rg) * 4 + h] = pl;
        er[(size_t)(rb + rg) * 4 + h] = pr;
      }
    }
    *(float4*)&C[(size_t)(rb + rg) * 128 + 4 * cg] = o;
  }
}

// ---------------- predictor: out = bnrelu(A) @ Wp + bp (40 cols) ----------------
__global__ __launch_bounds__(320) void k_pred(
    const float* __restrict__ A, const float* __restrict__ stats,
    const float* __restrict__ W, const float* __restrict__ bias,
    float* __restrict__ out, int n) {
  __shared__ float Wl[128 * 40];
  __shared__ float Xl[32 * 132];
  for (int i = threadIdx.x; i < 128 * 40; i += 320) Wl[i] = W[i];
  int cg = threadIdx.x % 10;  // cols 4cg..4cg+3
  int rg = threadIdx.x / 10;  // row 0..31
  float4 bv = *(const float4*)&bias[4 * cg];
  for (int rb = blockIdx.x * 32; rb < n; rb += gridDim.x * 32) {
    __syncthreads();
    for (int idx = threadIdx.x; idx < 1024; idx += 320) {
      int r = idx >> 5, c = (idx & 31) * 4;
      float4 v = *(const float4*)&A[(size_t)(rb + r) * 128 + c];
      float4 sc = *(const float4*)&stats[c];
      float4 sh = *(const float4*)&stats[128 + c];
      v.x = fmaxf(v.x * sc.x + sh.x, 0.f);
      v.y = fmaxf(v.y * sc.y + sh.y, 0.f);
      v.z = fmaxf(v.z * sc.z + sh.z, 0.f);
      v.w = fmaxf(v.w * sc.w + sh.w, 0.f);
      *(float4*)&Xl[r * 132 + c] = v;
    }
    __syncthreads();
    float a0 = 0.f, a1 = 0.f, a2 = 0.f, a3 = 0.f;
#pragma unroll 4
    for (int k = 0; k < 128; ++k) {
      float x = Xl[rg * 132 + k];
      float4 w = *(float4*)&Wl[k * 40 + 4 * cg];
      a0 += x * w.x; a1 += x * w.y; a2 += x * w.z; a3 += x * w.w;
    }
    float4 o = make_float4(a0 + bv.x, a1 + bv.y, a2 + bv.z, a3 + bv.w);
    *(float4*)&out[(size_t)(rb + rg) * 40 + 4 * cg] = o;
  }
}

// ---------------- per-node two-phase softmax aggregation (1 wave/node) ----------------
// Each lane handles 2 channels (c0=2*lane) of head h=lane>>4, and tracks only
// that head's max/sum. Phase 1: max. Phase 2: exp + accumulate, unrolled x2.
__global__ __launch_bounds__(256) void k_aggregate(
    const float* __restrict__ hf, const float* __restrict__ el,
    const float* __restrict__ er, const int* __restrict__ rowptr,
    const int* __restrict__ ssort, const float* __restrict__ bias,
    float* __restrict__ hpre, int n, int addres) {
  int gid = blockIdx.x * 256 + threadIdx.x;
  int wid = gid >> 6, lane = gid & 63;
  if (wid >= n) return;
  int beg = rowptr[wid], end = rowptr[wid + 1];
  int h = lane >> 4;
  int c0 = 2 * lane;
  float erh = er[4 * wid + h];
  float m = -1e30f;
  for (int j = beg; j < end; ++j) {
    float e = el[4 * ssort[j] + h] + erh;
    e = fmaxf(e, NEG * e);  // leaky_relu with slope 0.2 (valid since 0.2>0)
    m = fmaxf(m, e);
  }
  float s0 = 0.f, a00 = 0.f, a10 = 0.f;
  float s1 = 0.f, a01 = 0.f, a11 = 0.f;
  int j = beg;
  if ((end - beg) & 1) {
    int sidx = ssort[j];
    float e = el[4 * sidx + h] + erh;
    e = fmaxf(e, NEG * e);
    float w = __expf(e - m);
    float2 hv = *(const float2*)(hf + (size_t)sidx * 128 + c0);
    s0 += w; a00 += w * hv.x; a10 += w * hv.y;
    ++j;
  }
  for (; j < end; j += 2) {
    int sA = ssort[j], sB = ssort[j + 1];
    float eA = el[4 * sA + h] + erh;
    float eB = el[4 * sB + h] + erh;
    eA = fmaxf(eA, NEG * eA);
    eB = fmaxf(eB, NEG * eB);
    float wA = __expf(eA - m);
    float wB = __expf(eB - m);
    float2 hvA = *(const float2*)(hf + (size_t)sA * 128 + c0);
    float2 hvB = *(const float2*)(hf + (size_t)sB * 128 + c0);
    s0 += wA; a00 += wA * hvA.x; a10 += wA * hvA.y;
    s1 += wB; a01 += wB * hvB.x; a11 += wB * hvB.y;
  }
  float s = s0 + s1;
  float a0 = a00 + a01, a1 = a10 + a11;
  float inv = (end > beg) ? 1.f / s : 0.f;
  float2 res = make_float2(0.f, 0.f);
  if (addres) res = *(const float2*)(hpre + (size_t)wid * 128 + c0);
  float o0 = a0 * inv + bias[c0] + res.x;
  float o1 = a1 * inv + bias[c0 + 1] + res.y;
  *(float2*)(hpre + (size_t)wid * 128 + c0) = make_float2(o0, o1);
}

// ---------------- batchnorm stats ----------------
__global__ __launch_bounds__(256) void k_bnpart(const float* __restrict__ x,
                                                float* __restrict__ part, int n) {
  int c = threadIdx.x & 127;
  int half = threadIdx.x >> 7;
  float s = 0.f, q = 0.f;
  for (int r = blockIdx.x * 2 + half; r < n; r += gridDim.x * 2) {
    float v = x[(size_t)r * 128 + c];
    s += v; q += v * v;
  }
  __shared__ float sm[512];
  sm[threadIdx.x] = s; sm[256 + threadIdx.x] = q;
  __syncthreads();
  if (threadIdx.x < 128) {
    part[blockIdx.x * 256 + threadIdx.x] = sm[threadIdx.x] + sm[threadIdx.x + 128];
    part[blockIdx.x * 256 + 128 + threadIdx.x] =
        sm[256 + threadIdx.x] + sm[256 + threadIdx.x + 128];
  }
}

__global__ void k_bnfin(const float* __restrict__ part, const float* __restrict__ gamma,
                        const float* __restrict__ beta, float* __restrict__ stats,
                        int g, int n) {
  int c = threadIdx.x;  // 128 threads
  float s = 0.f, q = 0.f;
  for (int b = 0; b < g; ++b) {
    s += part[b * 256 + c];
    q += part[b * 256 + 128 + c];
  }
  float mean = s / n;
  float var = q / n - mean * mean;
  float rstd = rsqrtf(var + BN_EPS);
  float scale = gamma[c] * rstd;
  stats[c] = scale;
  stats[128 + c] = beta[c] - mean * scale;
}

extern "C" void kernel_launch(void* const* d_in, const int* in_sizes, int n_in,
                              void* d_out, int out_size, void* d_ws, size_t ws_size,
                              hipStream_t stream) {
  const float* feat   = (const float*)d_in[0];
  const int*   src    = (const int*)d_in[1];
  const int*   dst    = (const int*)d_in[2];
  const float* W_enc  = (const float*)d_in[3];
  const float* b_enc  = (const float*)d_in[4];
  const float* Ws     = (const float*)d_in[5];
  const float* a_ls   = (const float*)d_in[6];
  const float* a_rs   = (const float*)d_in[7];
  const float* biases = (const float*)d_in[8];
  const float* gammas = (const float*)d_in[9];
  const float* betas  = (const float*)d_in[10];
  const float* W_pred = (const float*)d_in[11];
  const float* b_pred = (const float*)d_in[12];
  float* out = (float*)d_out;

  char* p = (char*)d_ws;
  float* h    = (float*)p; p += (size_t)N_NODES * 128 * 4;
  float* hf   = (float*)p; p += (size_t)N_NODES * 128 * 4;
  float* hpre = (float*)p; p += (size_t)N_NODES * 128 * 4;
  float* el   = (float*)p; p += (size_t)N_NODES * 4 * 4;
  float* er   = (float*)p; p += (size_t)N_NODES * 4 * 4;
  float* part = (float*)p; p += (size_t)G_BN * 256 * 4;
  float* stats= (float*)p; p += 256 * 4;
  int* rowptr = (int*)p;   p += (size_t)(N_NODES + 1) * 4;
  int* cursor = (int*)p;   p += (size_t)N_NODES * 4;
  int* bsums  = (int*)p;   p += 512 * 4;
  int* ssort  = (int*)p;   p += (size_t)N_EDGES * 4;

  // CSR build (dst-sorted)
  hipMemsetAsync(cursor, 0, (size_t)N_NODES * 4, stream);
  k_hist<<<(N_EDGES + 255) / 256, 256, 0, stream>>>(dst, cursor, N_EDGES);
  int nb = (N_NODES + 255) / 256;  // 391
  k_scan1<<<nb, 256, 0, stream>>>(cursor, rowptr, bsums, N_NODES);
  k_scan2<<<1, 512, 0, stream>>>(bsums, nb);
  k_scan3<<<nb, 256, 0, stream>>>(rowptr, bsums, cursor, N_NODES);
  k_scatter<<<(N_EDGES + 255) / 256, 256, 0, stream>>>(src, dst, cursor, ssort, N_EDGES);

  // encoder: h = relu(feat @ W_enc + b_enc)
  k_gemm128<1><<<1024, 256, 0, stream>>>(feat, W_enc, b_enc, nullptr, nullptr, nullptr,
                                         nullptr, nullptr, h, N_NODES);

  int aggblocks = (N_NODES * 64 + 255) / 256;  // 25000
  for (int L = 0; L < 3; ++L) {
    const float* al = a_ls + L * 128;
    const float* ar = a_rs + L * 128;
    if (L == 0)
      k_gemm128<4><<<1024, 256, 0, stream>>>(h, Ws + (size_t)L * 16384, nullptr, nullptr,
                                             al, ar, el, er, hf, N_NODES);
    else
      k_gemm128<6><<<1024, 256, 0, stream>>>(hpre, Ws + (size_t)L * 16384, nullptr, stats,
                                             al, ar, el, er, hf, N_NODES);
    k_aggregate<<<aggblocks, 256, 0, stream>>>(hf, el, er, rowptr, ssort,
                                               biases + L * 128, hpre, N_NODES,
                                               L > 0 ? 1 : 0);
    k_bnpart<<<G_BN, 256, 0, stream>>>(hpre, part, N_NODES);
    k_bnfin<<<1, 128, 0, stream>>>(part, gammas + L * 128, betas + L * 128, stats, G_BN,
                                   N_NODES);
  }
  // predictor uses layer-2 BN stats
  k_pred<<<512, 320, 0, stream>>>(hpre, stats, W_pred, b_pred, out, N_NODES);
}

// Round 3
// 781.137 us; speedup vs baseline: 1.5448x; 1.4766x over previous
//
#include <hip/hip_runtime.h>

typedef __attribute__((ext_vector_type(8))) short short8;
typedef __attribute__((ext_vector_type(4))) float f32x4;

#define N_NODES 100000
#define N_EDGES 800000
#define NEG 0.2f
#define BN_EPS 1e-5f
#define G_BN 240

__device__ __forceinline__ ushort bf16b(float f) {
  unsigned u = __float_as_uint(f);
  return (ushort)((u + 0x7FFFu + ((u >> 16) & 1u)) >> 16);
}
__device__ __forceinline__ float bflo(unsigned u) { return __uint_as_float(u << 16); }
__device__ __forceinline__ float bfhi(unsigned u) { return __uint_as_float(u & 0xFFFF0000u); }

// ---------------- CSR build (dst-sorted edge list) ----------------
__global__ void k_hist(const int* __restrict__ dst, int* __restrict__ cnt, int e) {
  int i = blockIdx.x * blockDim.x + threadIdx.x;
  if (i < e) atomicAdd(&cnt[dst[i]], 1);
}

__global__ void k_scan1(const int* __restrict__ cnt, int* __restrict__ rowptr,
                        int* __restrict__ bsums, int n) {
  __shared__ int sm[256];
  int i = blockIdx.x * 256 + threadIdx.x;
  int v = (i < n) ? cnt[i] : 0;
  sm[threadIdx.x] = v;
  __syncthreads();
  for (int off = 1; off < 256; off <<= 1) {
    int t = (threadIdx.x >= off) ? sm[threadIdx.x - off] : 0;
    __syncthreads();
    sm[threadIdx.x] += t;
    __syncthreads();
  }
  if (i < n) rowptr[i + 1] = sm[threadIdx.x];
  if (threadIdx.x == 255) bsums[blockIdx.x] = sm[255];
}

__global__ void k_scan2(int* __restrict__ bsums, int nb) {
  __shared__ int sm[512];
  int v = (threadIdx.x < nb) ? bsums[threadIdx.x] : 0;
  sm[threadIdx.x] = v;
  __syncthreads();
  for (int off = 1; off < 512; off <<= 1) {
    int t = (threadIdx.x >= off) ? sm[threadIdx.x - off] : 0;
    __syncthreads();
    sm[threadIdx.x] += t;
    __syncthreads();
  }
  if (threadIdx.x < nb) bsums[threadIdx.x] = sm[threadIdx.x] - v;  // exclusive
}

__global__ void k_scan3(int* __restrict__ rowptr, const int* __restrict__ bsums,
                        int* __restrict__ cursor, int n) {
  int i = blockIdx.x * 256 + threadIdx.x;
  if (i < n) {
    int val = rowptr[i + 1] + bsums[blockIdx.x];
    rowptr[i + 1] = val;
    if (i + 1 < n) cursor[i + 1] = val;
  }
  if (i == 0) { rowptr[0] = 0; cursor[0] = 0; }
}

__global__ void k_scatter(const int* __restrict__ src, const int* __restrict__ dst,
                          int* __restrict__ cursor, int* __restrict__ ssort, int e) {
  int i = blockIdx.x * blockDim.x + threadIdx.x;
  if (i < e) {
    int pos = atomicAdd(&cursor[dst[i]], 1);
    ssort[pos] = src[i];
  }
}

// ---------------- pack 4 weight matrices into MFMA B-fragment order (bf16) --------
// slot s2 = ((kt*8 + nb8)*64 + lane); element e -> W[kt*32 + (lane>>4)*8 + e][nb8*16 + (lane&15)]
__global__ void k_packW(const float* __restrict__ W_enc, const float* __restrict__ Ws,
                        ushort* __restrict__ Wp) {
  int s = blockIdx.x * 256 + threadIdx.x;  // 4 * 2048 slots
  int wi = s >> 11, s2 = s & 2047;
  int kt = s2 >> 9, nb8 = (s2 >> 6) & 7, l = s2 & 63;
  const float* Wsrc = (wi == 0) ? W_enc : Ws + (size_t)(wi - 1) * 16384;
  int n = nb8 * 16 + (l & 15);
  int k0 = kt * 32 + (l >> 4) * 8;
  unsigned pk[4];
#pragma unroll
  for (int j = 0; j < 4; ++j) {
    ushort lo = bf16b(Wsrc[(size_t)(k0 + 2 * j) * 128 + n]);
    ushort hi = bf16b(Wsrc[(size_t)(k0 + 2 * j + 1) * 128 + n]);
    pk[j] = (unsigned)lo | ((unsigned)hi << 16);
  }
  *(uint4*)&Wp[(size_t)s * 8] = make_uint4(pk[0], pk[1], pk[2], pk[3]);
}

// ---------------- MFMA GEMM: Cb(bf16) = act(A @ W), optional el/er epilogue ------
// MODE 0: encoder (A fp32, epilogue +bias relu, no el/er)
// MODE 1: layer 0 (A bf16, el/er epilogue)
// MODE 2: layer 1/2 (A fp32 with fused BN+relu, el/er epilogue)
template <int MODE>
__global__ __launch_bounds__(256) void k_mgemm(
    const float* __restrict__ Af, const ushort* __restrict__ Ab,
    const ushort* __restrict__ Wp, const float* __restrict__ bias,
    const float* __restrict__ stats, const float* __restrict__ al,
    const float* __restrict__ ar, float* __restrict__ el, float* __restrict__ er,
    ushort* __restrict__ Cb) {
  __shared__ __align__(16) ushort Al[32 * 128];
  int tid = threadIdx.x;
  int lane = tid & 63, w = tid >> 6;
  int wr = w & 1, wc = w >> 1;
  int l15 = lane & 15, l4 = lane >> 4;
  int rb = blockIdx.x * 32;

  // B fragments from packed W (L2/L3-resident), consistent k-permutation with A
  const uint4* wp4 = (const uint4*)Wp;
  short8 bfr[4][4];
#pragma unroll
  for (int kt = 0; kt < 4; ++kt) {
#pragma unroll
    for (int nb = 0; nb < 4; ++nb) {
      uint4 t = wp4[(size_t)((kt * 8 + wc * 4 + nb) * 64 + lane)];
      bfr[kt][nb] = *(short8*)&t;
    }
  }

  // stage A tile: 32 rows x 128 cols bf16, XOR-swizzled 16B chunks
  {
    int row = tid >> 3;
    int c16 = (tid & 7) * 16;
    int kc0 = (tid & 7) * 2;
    char* base = (char*)Al + row * 256;
    if (MODE == 1) {
      const uint4* srcp = (const uint4*)(Ab + (size_t)(rb + row) * 128 + c16);
      uint4 v0 = srcp[0], v1 = srcp[1];
      *(uint4*)(base + ((kc0 ^ (row & 7)) << 4)) = v0;
      *(uint4*)(base + (((kc0 + 1) ^ (row & 7)) << 4)) = v1;
    } else {
      const float4* srcp = (const float4*)(Af + (size_t)(rb + row) * 128 + c16);
      float4 f[4];
#pragma unroll
      for (int j = 0; j < 4; ++j) f[j] = srcp[j];
      if (MODE == 2) {
#pragma unroll
        for (int j = 0; j < 4; ++j) {
          float4 sc = *(const float4*)&stats[c16 + 4 * j];
          float4 sh = *(const float4*)&stats[128 + c16 + 4 * j];
          f[j].x = fmaxf(f[j].x * sc.x + sh.x, 0.f);
          f[j].y = fmaxf(f[j].y * sc.y + sh.y, 0.f);
          f[j].z = fmaxf(f[j].z * sc.z + sh.z, 0.f);
          f[j].w = fmaxf(f[j].w * sc.w + sh.w, 0.f);
        }
      }
      unsigned pk[8];
#pragma unroll
      for (int j = 0; j < 4; ++j) {
        pk[2 * j] = (unsigned)bf16b(f[j].x) | ((unsigned)bf16b(f[j].y) << 16);
        pk[2 * j + 1] = (unsigned)bf16b(f[j].z) | ((unsigned)bf16b(f[j].w) << 16);
      }
      *(uint4*)(base + ((kc0 ^ (row & 7)) << 4)) = make_uint4(pk[0], pk[1], pk[2], pk[3]);
      *(uint4*)(base + (((kc0 + 1) ^ (row & 7)) << 4)) = make_uint4(pk[4], pk[5], pk[6], pk[7]);
    }
  }
  __syncthreads();

  f32x4 acc[4];
#pragma unroll
  for (int nb = 0; nb < 4; ++nb) acc[nb] = (f32x4){0.f, 0.f, 0.f, 0.f};
  int arow = 16 * wr + l15;
  const char* abase = (const char*)Al + arow * 256;
  int sw = arow & 7;
#pragma unroll
  for (int kt = 0; kt < 4; ++kt) {
    short8 af = *(const short8*)(abase + (((kt * 4 + l4) ^ sw) << 4));
    acc[0] = __builtin_amdgcn_mfma_f32_16x16x32_bf16(af, bfr[kt][0], acc[0], 0, 0, 0);
    acc[1] = __builtin_amdgcn_mfma_f32_16x16x32_bf16(af, bfr[kt][1], acc[1], 0, 0, 0);
    acc[2] = __builtin_amdgcn_mfma_f32_16x16x32_bf16(af, bfr[kt][2], acc[2], 0, 0, 0);
    acc[3] = __builtin_amdgcn_mfma_f32_16x16x32_bf16(af, bfr[kt][3], acc[3], 0, 0, 0);
  }

  // epilogue
  float alv0 = 0, alv1 = 0, alv2 = 0, alv3 = 0;
  float arv0 = 0, arv1 = 0, arv2 = 0, arv3 = 0;
  float bv0 = 0, bv1 = 0, bv2 = 0, bv3 = 0;
  if (MODE != 0) {
    alv0 = al[64 * wc + l15];      arv0 = ar[64 * wc + l15];
    alv1 = al[64 * wc + 16 + l15]; arv1 = ar[64 * wc + 16 + l15];
    alv2 = al[64 * wc + 32 + l15]; arv2 = ar[64 * wc + 32 + l15];
    alv3 = al[64 * wc + 48 + l15]; arv3 = ar[64 * wc + 48 + l15];
  } else {
    bv0 = bias[64 * wc + l15];      bv1 = bias[64 * wc + 16 + l15];
    bv2 = bias[64 * wc + 32 + l15]; bv3 = bias[64 * wc + 48 + l15];
  }
  int row0 = rb + 16 * wr + 4 * l4;
#pragma unroll
  for (int i = 0; i < 4; ++i) {
    int row = row0 + i;
    if (MODE != 0) {
      float pl0 = acc[0][i] * alv0 + acc[1][i] * alv1;
      float pr0 = acc[0][i] * arv0 + acc[1][i] * arv1;
      float pl1 = acc[2][i] * alv2 + acc[3][i] * alv3;
      float pr1 = acc[2][i] * arv2 + acc[3][i] * arv3;
#pragma unroll
      for (int o = 1; o < 16; o <<= 1) {
        pl0 += __shfl_xor(pl0, o); pr0 += __shfl_xor(pr0, o);
        pl1 += __shfl_xor(pl1, o); pr1 += __shfl_xor(pr1, o);
      }
      if (l15 == 0) {
        el[(size_t)row * 4 + 2 * wc] = pl0;     er[(size_t)row * 4 + 2 * wc] = pr0;
        el[(size_t)row * 4 + 2 * wc + 1] = pl1; er[(size_t)row * 4 + 2 * wc + 1] = pr1;
      }
    }
    float v0 = acc[0][i], v1 = acc[1][i], v2 = acc[2][i], v3 = acc[3][i];
    if (MODE == 0) {
      v0 = fmaxf(v0 + bv0, 0.f); v1 = fmaxf(v1 + bv1, 0.f);
      v2 = fmaxf(v2 + bv2, 0.f); v3 = fmaxf(v3 + bv3, 0.f);
    }
    size_t rbase = (size_t)row * 128 + 64 * wc + l15;
    Cb[rbase] = bf16b(v0);
    Cb[rbase + 16] = bf16b(v1);
    Cb[rbase + 32] = bf16b(v2);
    Cb[rbase + 48] = bf16b(v3);
  }
}

// ---------------- global per-head max of el (softmax upper bound) ----------------
__global__ __launch_bounds__(256) void k_elmax1(const float* __restrict__ el,
                                                float4* __restrict__ part, int n) {
  int gid = blockIdx.x * 256 + threadIdx.x;
  float4 m = make_float4(-1e30f, -1e30f, -1e30f, -1e30f);
  for (int i = gid; i < n; i += 128 * 256) {
    float4 v = *(const float4*)&el[(size_t)4 * i];
    m.x = fmaxf(m.x, v.x); m.y = fmaxf(m.y, v.y);
    m.z = fmaxf(m.z, v.z); m.w = fmaxf(m.w, v.w);
  }
  __shared__ float4 sm[256];
  sm[threadIdx.x] = m;
  __syncthreads();
  for (int off = 128; off; off >>= 1) {
    if (threadIdx.x < off) {
      float4 o = sm[threadIdx.x + off];
      sm[threadIdx.x].x = fmaxf(sm[threadIdx.x].x, o.x);
      sm[threadIdx.x].y = fmaxf(sm[threadIdx.x].y, o.y);
      sm[threadIdx.x].z = fmaxf(sm[threadIdx.x].z, o.z);
      sm[threadIdx.x].w = fmaxf(sm[threadIdx.x].w, o.w);
    }
    __syncthreads();
  }
  if (threadIdx.x == 0) part[blockIdx.x] = sm[0];
}

__global__ void k_elmax2(const float4* __restrict__ part, float* __restrict__ elmax) {
  __shared__ float4 sm[128];
  int t = threadIdx.x;
  sm[t] = part[t];
  __syncthreads();
  for (int off = 64; off; off >>= 1) {
    if (t < off) {
      float4 o = sm[t + off];
      sm[t].x = fmaxf(sm[t].x, o.x);
      sm[t].y = fmaxf(sm[t].y, o.y);
      sm[t].z = fmaxf(sm[t].z, o.z);
      sm[t].w = fmaxf(sm[t].w, o.w);
    }
    __syncthreads();
  }
  if (t == 0) {
    elmax[0] = sm[0].x; elmax[1] = sm[0].y;
    elmax[2] = sm[0].z; elmax[3] = sm[0].w;
  }
}

// ---------------- single-pass softmax aggregation (1 wave/node, bf16 gather) -----
__global__ __launch_bounds__(256) void k_aggregate(
    const ushort* __restrict__ hf, const float* __restrict__ el,
    const float* __restrict__ er, const int* __restrict__ rowptr,
    const int* __restrict__ ssort, const float* __restrict__ bias,
    const float* __restrict__ elmax, float* __restrict__ hpre, int n, int addres) {
  int gid = blockIdx.x * 256 + threadIdx.x;
  int wid = gid >> 6, lane = gid & 63;
  if (wid >= n) return;
  int beg = rowptr[wid], end = rowptr[wid + 1];
  int h = lane >> 4;
  int c0 = 2 * lane;
  float erh = er[(size_t)4 * wid + h];
  // upper bound on e over in-edges: leaky is monotone, el <= elmax[h]
  float mu = elmax[h] + erh;
  mu = fmaxf(mu, NEG * mu);
  float s0 = 0.f, a00 = 0.f, a10 = 0.f;
  float s1 = 0.f, a01 = 0.f, a11 = 0.f;
  int j = beg;
  if ((end - beg) & 1) {
    int sidx = ssort[j];
    float e = el[(size_t)4 * sidx + h] + erh;
    e = fmaxf(e, NEG * e);
    float wgt = __expf(e - mu);
    unsigned hv = *(const unsigned*)(hf + (size_t)sidx * 128 + c0);
    s0 += wgt; a00 += wgt * bflo(hv); a10 += wgt * bfhi(hv);
    ++j;
  }
  for (; j < end; j += 2) {
    int sA = ssort[j], sB = ssort[j + 1];
    float eA = el[(size_t)4 * sA + h] + erh;
    float eB = el[(size_t)4 * sB + h] + erh;
    eA = fmaxf(eA, NEG * eA);
    eB = fmaxf(eB, NEG * eB);
    float wA = __expf(eA - mu), wB = __expf(eB - mu);
    unsigned hA = *(const unsigned*)(hf + (size_t)sA * 128 + c0);
    unsigned hB = *(const unsigned*)(hf + (size_t)sB * 128 + c0);
    s0 += wA; a00 += wA * bflo(hA); a10 += wA * bfhi(hA);
    s1 += wB; a01 += wB * bflo(hB); a11 += wB * bfhi(hB);
  }
  float s = s0 + s1;
  float inv = (end > beg) ? 1.f / s : 0.f;
  float a0 = (a00 + a01) * inv, a1 = (a10 + a11) * inv;
  float2 bb = *(const float2*)&bias[c0];
  float2 res = make_float2(0.f, 0.f);
  if (addres) res = *(const float2*)(hpre + (size_t)wid * 128 + c0);
  *(float2*)(hpre + (size_t)wid * 128 + c0) =
      make_float2(a0 + bb.x + res.x, a1 + bb.y + res.y);
}

// ---------------- predictor: out = bnrelu(A) @ Wp + bp (40 cols, fp32) -----------
__global__ __launch_bounds__(320) void k_pred(
    const float* __restrict__ A, const float* __restrict__ stats,
    const float* __restrict__ W, const float* __restrict__ bias,
    float* __restrict__ out, int n) {
  __shared__ float Wl[128 * 40];
  __shared__ float Xl[32 * 132];
  for (int i = threadIdx.x; i < 128 * 40; i += 320) Wl[i] = W[i];
  int cg = threadIdx.x % 10;
  int rg = threadIdx.x / 10;
  float4 bv = *(const float4*)&bias[4 * cg];
  for (int rb = blockIdx.x * 32; rb < n; rb += gridDim.x * 32) {
    __syncthreads();
    for (int idx = threadIdx.x; idx < 1024; idx += 320) {
      int r = idx >> 5, c = (idx & 31) * 4;
      float4 v = *(const float4*)&A[(size_t)(rb + r) * 128 + c];
      float4 sc = *(const float4*)&stats[c];
      float4 sh = *(const float4*)&stats[128 + c];
      v.x = fmaxf(v.x * sc.x + sh.x, 0.f);
      v.y = fmaxf(v.y * sc.y + sh.y, 0.f);
      v.z = fmaxf(v.z * sc.z + sh.z, 0.f);
      v.w = fmaxf(v.w * sc.w + sh.w, 0.f);
      *(float4*)&Xl[r * 132 + c] = v;
    }
    __syncthreads();
    float a0 = 0.f, a1 = 0.f, a2 = 0.f, a3 = 0.f;
#pragma unroll 4
    for (int k = 0; k < 128; ++k) {
      float x = Xl[rg * 132 + k];
      float4 w = *(float4*)&Wl[k * 40 + 4 * cg];
      a0 += x * w.x; a1 += x * w.y; a2 += x * w.z; a3 += x * w.w;
    }
    float4 o = make_float4(a0 + bv.x, a1 + bv.y, a2 + bv.z, a3 + bv.w);
    *(float4*)&out[(size_t)(rb + rg) * 40 + 4 * cg] = o;
  }
}

// ---------------- batchnorm stats ----------------
__global__ __launch_bounds__(256) void k_bnpart(const float* __restrict__ x,
                                                float* __restrict__ part, int n) {
  int c = threadIdx.x & 127;
  int half = threadIdx.x >> 7;
  float s = 0.f, q = 0.f;
  for (int r = blockIdx.x * 2 + half; r < n; r += gridDim.x * 2) {
    float v = x[(size_t)r * 128 + c];
    s += v; q += v * v;
  }
  __shared__ float sm[512];
  sm[threadIdx.x] = s; sm[256 + threadIdx.x] = q;
  __syncthreads();
  if (threadIdx.x < 128) {
    part[blockIdx.x * 256 + threadIdx.x] = sm[threadIdx.x] + sm[threadIdx.x + 128];
    part[blockIdx.x * 256 + 128 + threadIdx.x] =
        sm[256 + threadIdx.x] + sm[256 + threadIdx.x + 128];
  }
}

__global__ void k_bnfin(const float* __restrict__ part, const float* __restrict__ gamma,
                        const float* __restrict__ beta, float* __restrict__ stats,
                        int g, int n) {
  int c = threadIdx.x;
  float s = 0.f, q = 0.f;
  for (int b = 0; b < g; ++b) {
    s += part[b * 256 + c];
    q += part[b * 256 + 128 + c];
  }
  float mean = s / n;
  float var = q / n - mean * mean;
  float rstd = rsqrtf(var + BN_EPS);
  float scale = gamma[c] * rstd;
  stats[c] = scale;
  stats[128 + c] = beta[c] - mean * scale;
}

extern "C" void kernel_launch(void* const* d_in, const int* in_sizes, int n_in,
                              void* d_out, int out_size, void* d_ws, size_t ws_size,
                              hipStream_t stream) {
  const float* feat   = (const float*)d_in[0];
  const int*   src    = (const int*)d_in[1];
  const int*   dst    = (const int*)d_in[2];
  const float* W_enc  = (const float*)d_in[3];
  const float* b_enc  = (const float*)d_in[4];
  const float* Ws     = (const float*)d_in[5];
  const float* a_ls   = (const float*)d_in[6];
  const float* a_rs   = (const float*)d_in[7];
  const float* biases = (const float*)d_in[8];
  const float* gammas = (const float*)d_in[9];
  const float* betas  = (const float*)d_in[10];
  const float* W_pred = (const float*)d_in[11];
  const float* b_pred = (const float*)d_in[12];
  float* out = (float*)d_out;

  char* p = (char*)d_ws;
  auto alloc = [&](size_t bytes) {
    char* q = p;
    p += (bytes + 255) & ~(size_t)255;
    return q;
  };
  ushort* h_bf  = (ushort*)alloc((size_t)N_NODES * 128 * 2);
  ushort* hf_bf = (ushort*)alloc((size_t)N_NODES * 128 * 2);
  float* hpre   = (float*)alloc((size_t)N_NODES * 128 * 4);
  float* el     = (float*)alloc((size_t)N_NODES * 4 * 4);
  float* er     = (float*)alloc((size_t)N_NODES * 4 * 4);
  float* part   = (float*)alloc((size_t)G_BN * 256 * 4);
  float* stats  = (float*)alloc(256 * 4);
  ushort* Wpack = (ushort*)alloc((size_t)4 * 2048 * 16);
  float4* elpart= (float4*)alloc(128 * 16);
  float* elmax  = (float*)alloc(4 * 4);
  int* rowptr   = (int*)alloc((size_t)(N_NODES + 1) * 4);
  int* cursor   = (int*)alloc((size_t)N_NODES * 4);
  int* bsums    = (int*)alloc(512 * 4);
  int* ssort    = (int*)alloc((size_t)N_EDGES * 4);

  // CSR build (dst-sorted)
  hipMemsetAsync(cursor, 0, (size_t)N_NODES * 4, stream);
  k_hist<<<(N_EDGES + 255) / 256, 256, 0, stream>>>(dst, cursor, N_EDGES);
  int nb = (N_NODES + 255) / 256;  // 391
  k_scan1<<<nb, 256, 0, stream>>>(cursor, rowptr, bsums, N_NODES);
  k_scan2<<<1, 512, 0, stream>>>(bsums, nb);
  k_scan3<<<nb, 256, 0, stream>>>(rowptr, bsums, cursor, N_NODES);
  k_scatter<<<(N_EDGES + 255) / 256, 256, 0, stream>>>(src, dst, cursor, ssort, N_EDGES);

  // pack weights to MFMA fragment order
  k_packW<<<32, 256, 0, stream>>>(W_enc, Ws, Wpack);

  // encoder: h = relu(feat @ W_enc + b_enc), stored bf16
  k_mgemm<0><<<3125, 256, 0, stream>>>(feat, nullptr, Wpack, b_enc, nullptr, nullptr,
                                       nullptr, nullptr, nullptr, h_bf);

  int aggblocks = (N_NODES * 64 + 255) / 256;  // 25000
  for (int L = 0; L < 3; ++L) {
    const float* al = a_ls + L * 128;
    const float* ar = a_rs + L * 128;
    const ushort* wp = Wpack + (size_t)(1 + L) * 16384;
    if (L == 0)
      k_mgemm<1><<<3125, 256, 0, stream>>>(nullptr, h_bf, wp, nullptr, nullptr, al, ar,
                                           el, er, hf_bf);
    else
      k_mgemm<2><<<3125, 256, 0, stream>>>(hpre, nullptr, wp, nullptr, stats, al, ar,
                                           el, er, hf_bf);
    k_elmax1<<<128, 256, 0, stream>>>(el, elpart, N_NODES);
    k_elmax2<<<1, 128, 0, stream>>>(elpart, elmax);
    k_aggregate<<<aggblocks, 256, 0, stream>>>(hf_bf, el, er, rowptr, ssort,
                                               biases + L * 128, elmax, hpre, N_NODES,
                                               L > 0 ? 1 : 0);
    k_bnpart<<<G_BN, 256, 0, stream>>>(hpre, part, N_NODES);
    k_bnfin<<<1, 128, 0, stream>>>(part, gammas + L * 128, betas + L * 128, stats, G_BN,
                                   N_NODES);
  }
  // predictor uses layer-2 BN stats
  k_pred<<<512, 320, 0, stream>>>(hpre, stats, W_pred, b_pred, out, N_NODES);
}

// Round 4
// 680.376 us; speedup vs baseline: 1.7735x; 1.1481x over previous
//
#include <hip/hip_runtime.h>

typedef __attribute__((ext_vector_type(8))) short short8;
typedef __attribute__((ext_vector_type(4))) float f32x4;

#define N_NODES 100000
#define N_EDGES 800000
#define NEG 0.2f
#define BN_EPS 1e-5f
#define G_BN 1200

__device__ __forceinline__ ushort bf16b(float f) {
  unsigned u = __float_as_uint(f);
  return (ushort)((u + 0x7FFFu + ((u >> 16) & 1u)) >> 16);
}
__device__ __forceinline__ float bflo(unsigned u) { return __uint_as_float(u << 16); }
__device__ __forceinline__ float bfhi(unsigned u) { return __uint_as_float(u & 0xFFFF0000u); }

// ---------------- CSR build (dst-sorted edge list) ----------------
__global__ void k_hist(const int* __restrict__ dst, int* __restrict__ cnt, int e) {
  int i = blockIdx.x * blockDim.x + threadIdx.x;
  if (i < e) atomicAdd(&cnt[dst[i]], 1);
}

__global__ void k_scan1(const int* __restrict__ cnt, int* __restrict__ rowptr,
                        int* __restrict__ bsums, int n) {
  __shared__ int sm[256];
  int i = blockIdx.x * 256 + threadIdx.x;
  int v = (i < n) ? cnt[i] : 0;
  sm[threadIdx.x] = v;
  __syncthreads();
  for (int off = 1; off < 256; off <<= 1) {
    int t = (threadIdx.x >= off) ? sm[threadIdx.x - off] : 0;
    __syncthreads();
    sm[threadIdx.x] += t;
    __syncthreads();
  }
  if (i < n) rowptr[i + 1] = sm[threadIdx.x];
  if (threadIdx.x == 255) bsums[blockIdx.x] = sm[255];
}

__global__ void k_scan2(int* __restrict__ bsums, int nb) {
  __shared__ int sm[512];
  int v = (threadIdx.x < nb) ? bsums[threadIdx.x] : 0;
  sm[threadIdx.x] = v;
  __syncthreads();
  for (int off = 1; off < 512; off <<= 1) {
    int t = (threadIdx.x >= off) ? sm[threadIdx.x - off] : 0;
    __syncthreads();
    sm[threadIdx.x] += t;
    __syncthreads();
  }
  if (threadIdx.x < nb) bsums[threadIdx.x] = sm[threadIdx.x] - v;  // exclusive
}

__global__ void k_scan3(int* __restrict__ rowptr, const int* __restrict__ bsums,
                        int* __restrict__ cursor, int n) {
  int i = blockIdx.x * 256 + threadIdx.x;
  if (i < n) {
    int val = rowptr[i + 1] + bsums[blockIdx.x];
    rowptr[i + 1] = val;
    if (i + 1 < n) cursor[i + 1] = val;
  }
  if (i == 0) { rowptr[0] = 0; cursor[0] = 0; }
}

__global__ void k_scatter(const int* __restrict__ src, const int* __restrict__ dst,
                          int* __restrict__ cursor, int* __restrict__ ssort, int e) {
  int i = blockIdx.x * blockDim.x + threadIdx.x;
  if (i < e) {
    int pos = atomicAdd(&cursor[dst[i]], 1);
    ssort[pos] = src[i];
  }
}

// ---------------- pack 4 weight matrices into MFMA B-fragment order (bf16) --------
__global__ void k_packW(const float* __restrict__ W_enc, const float* __restrict__ Ws,
                        ushort* __restrict__ Wp) {
  int s = blockIdx.x * 256 + threadIdx.x;  // 4 * 2048 slots
  int wi = s >> 11, s2 = s & 2047;
  int kt = s2 >> 9, nb8 = (s2 >> 6) & 7, l = s2 & 63;
  const float* Wsrc = (wi == 0) ? W_enc : Ws + (size_t)(wi - 1) * 16384;
  int n = nb8 * 16 + (l & 15);
  int k0 = kt * 32 + (l >> 4) * 8;
  unsigned pk[4];
#pragma unroll
  for (int j = 0; j < 4; ++j) {
    ushort lo = bf16b(Wsrc[(size_t)(k0 + 2 * j) * 128 + n]);
    ushort hi = bf16b(Wsrc[(size_t)(k0 + 2 * j + 1) * 128 + n]);
    pk[j] = (unsigned)lo | ((unsigned)hi << 16);
  }
  *(uint4*)&Wp[(size_t)s * 8] = make_uint4(pk[0], pk[1], pk[2], pk[3]);
}

// ---------------- MFMA GEMM: Cb(bf16) = act(A @ W), optional el/er epilogue ------
// MODE 0: encoder (A fp32, epilogue +bias relu, no el/er)
// MODE 1: layer 0 (A bf16, el/er epilogue)
// MODE 2: layer 1/2 (A fp32 with fused BN+relu, el/er epilogue)
template <int MODE>
__global__ __launch_bounds__(256) void k_mgemm(
    const float* __restrict__ Af, const ushort* __restrict__ Ab,
    const ushort* __restrict__ Wp, const float* __restrict__ bias,
    const float* __restrict__ stats, const float* __restrict__ al,
    const float* __restrict__ ar, float* __restrict__ el, float* __restrict__ er,
    ushort* __restrict__ Cb) {
  __shared__ __align__(16) ushort Al[32 * 128];
  int tid = threadIdx.x;
  int lane = tid & 63, w = tid >> 6;
  int wr = w & 1, wc = w >> 1;
  int l15 = lane & 15, l4 = lane >> 4;
  int rb = blockIdx.x * 32;

  const uint4* wp4 = (const uint4*)Wp;
  short8 bfr[4][4];
#pragma unroll
  for (int kt = 0; kt < 4; ++kt) {
#pragma unroll
    for (int nb = 0; nb < 4; ++nb) {
      uint4 t = wp4[(size_t)((kt * 8 + wc * 4 + nb) * 64 + lane)];
      bfr[kt][nb] = *(short8*)&t;
    }
  }

  // stage A tile: 32 rows x 128 cols bf16, XOR-swizzled 16B chunks
  {
    int row = tid >> 3;
    int c16 = (tid & 7) * 16;
    int kc0 = (tid & 7) * 2;
    char* base = (char*)Al + row * 256;
    if (MODE == 1) {
      const uint4* srcp = (const uint4*)(Ab + (size_t)(rb + row) * 128 + c16);
      uint4 v0 = srcp[0], v1 = srcp[1];
      *(uint4*)(base + ((kc0 ^ (row & 7)) << 4)) = v0;
      *(uint4*)(base + (((kc0 + 1) ^ (row & 7)) << 4)) = v1;
    } else {
      const float4* srcp = (const float4*)(Af + (size_t)(rb + row) * 128 + c16);
      float4 f[4];
#pragma unroll
      for (int j = 0; j < 4; ++j) f[j] = srcp[j];
      if (MODE == 2) {
#pragma unroll
        for (int j = 0; j < 4; ++j) {
          float4 sc = *(const float4*)&stats[c16 + 4 * j];
          float4 sh = *(const float4*)&stats[128 + c16 + 4 * j];
          f[j].x = fmaxf(f[j].x * sc.x + sh.x, 0.f);
          f[j].y = fmaxf(f[j].y * sc.y + sh.y, 0.f);
          f[j].z = fmaxf(f[j].z * sc.z + sh.z, 0.f);
          f[j].w = fmaxf(f[j].w * sc.w + sh.w, 0.f);
        }
      }
      unsigned pk[8];
#pragma unroll
      for (int j = 0; j < 4; ++j) {
        pk[2 * j] = (unsigned)bf16b(f[j].x) | ((unsigned)bf16b(f[j].y) << 16);
        pk[2 * j + 1] = (unsigned)bf16b(f[j].z) | ((unsigned)bf16b(f[j].w) << 16);
      }
      *(uint4*)(base + ((kc0 ^ (row & 7)) << 4)) = make_uint4(pk[0], pk[1], pk[2], pk[3]);
      *(uint4*)(base + (((kc0 + 1) ^ (row & 7)) << 4)) = make_uint4(pk[4], pk[5], pk[6], pk[7]);
    }
  }
  __syncthreads();

  f32x4 acc[4];
#pragma unroll
  for (int nb = 0; nb < 4; ++nb) acc[nb] = (f32x4){0.f, 0.f, 0.f, 0.f};
  int arow = 16 * wr + l15;
  const char* abase = (const char*)Al + arow * 256;
  int sw = arow & 7;
#pragma unroll
  for (int kt = 0; kt < 4; ++kt) {
    short8 af = *(const short8*)(abase + (((kt * 4 + l4) ^ sw) << 4));
    acc[0] = __builtin_amdgcn_mfma_f32_16x16x32_bf16(af, bfr[kt][0], acc[0], 0, 0, 0);
    acc[1] = __builtin_amdgcn_mfma_f32_16x16x32_bf16(af, bfr[kt][1], acc[1], 0, 0, 0);
    acc[2] = __builtin_amdgcn_mfma_f32_16x16x32_bf16(af, bfr[kt][2], acc[2], 0, 0, 0);
    acc[3] = __builtin_amdgcn_mfma_f32_16x16x32_bf16(af, bfr[kt][3], acc[3], 0, 0, 0);
  }

  float alv0 = 0, alv1 = 0, alv2 = 0, alv3 = 0;
  float arv0 = 0, arv1 = 0, arv2 = 0, arv3 = 0;
  float bv0 = 0, bv1 = 0, bv2 = 0, bv3 = 0;
  if (MODE != 0) {
    alv0 = al[64 * wc + l15];      arv0 = ar[64 * wc + l15];
    alv1 = al[64 * wc + 16 + l15]; arv1 = ar[64 * wc + 16 + l15];
    alv2 = al[64 * wc + 32 + l15]; arv2 = ar[64 * wc + 32 + l15];
    alv3 = al[64 * wc + 48 + l15]; arv3 = ar[64 * wc + 48 + l15];
  } else {
    bv0 = bias[64 * wc + l15];      bv1 = bias[64 * wc + 16 + l15];
    bv2 = bias[64 * wc + 32 + l15]; bv3 = bias[64 * wc + 48 + l15];
  }
  int row0 = rb + 16 * wr + 4 * l4;
#pragma unroll
  for (int i = 0; i < 4; ++i) {
    int row = row0 + i;
    if (MODE != 0) {
      float pl0 = acc[0][i] * alv0 + acc[1][i] * alv1;
      float pr0 = acc[0][i] * arv0 + acc[1][i] * arv1;
      float pl1 = acc[2][i] * alv2 + acc[3][i] * alv3;
      float pr1 = acc[2][i] * arv2 + acc[3][i] * arv3;
#pragma unroll
      for (int o = 1; o < 16; o <<= 1) {
        pl0 += __shfl_xor(pl0, o); pr0 += __shfl_xor(pr0, o);
        pl1 += __shfl_xor(pl1, o); pr1 += __shfl_xor(pr1, o);
      }
      if (l15 == 0) {
        el[(size_t)row * 4 + 2 * wc] = pl0;     er[(size_t)row * 4 + 2 * wc] = pr0;
        el[(size_t)row * 4 + 2 * wc + 1] = pl1; er[(size_t)row * 4 + 2 * wc + 1] = pr1;
      }
    }
    float v0 = acc[0][i], v1 = acc[1][i], v2 = acc[2][i], v3 = acc[3][i];
    if (MODE == 0) {
      v0 = fmaxf(v0 + bv0, 0.f); v1 = fmaxf(v1 + bv1, 0.f);
      v2 = fmaxf(v2 + bv2, 0.f); v3 = fmaxf(v3 + bv3, 0.f);
    }
    size_t rbase = (size_t)row * 128 + 64 * wc + l15;
    Cb[rbase] = bf16b(v0);
    Cb[rbase + 16] = bf16b(v1);
    Cb[rbase + 32] = bf16b(v2);
    Cb[rbase + 48] = bf16b(v3);
  }
}

// ---------------- global per-head max of el (softmax upper bound) ----------------
__global__ __launch_bounds__(256) void k_elmax1(const float* __restrict__ el,
                                                float4* __restrict__ part, int n) {
  int gid = blockIdx.x * 256 + threadIdx.x;
  float4 m = make_float4(-1e30f, -1e30f, -1e30f, -1e30f);
  for (int i = gid; i < n; i += 128 * 256) {
    float4 v = *(const float4*)&el[(size_t)4 * i];
    m.x = fmaxf(m.x, v.x); m.y = fmaxf(m.y, v.y);
    m.z = fmaxf(m.z, v.z); m.w = fmaxf(m.w, v.w);
  }
  __shared__ float4 sm[256];
  sm[threadIdx.x] = m;
  __syncthreads();
  for (int off = 128; off; off >>= 1) {
    if (threadIdx.x < off) {
      float4 o = sm[threadIdx.x + off];
      sm[threadIdx.x].x = fmaxf(sm[threadIdx.x].x, o.x);
      sm[threadIdx.x].y = fmaxf(sm[threadIdx.x].y, o.y);
      sm[threadIdx.x].z = fmaxf(sm[threadIdx.x].z, o.z);
      sm[threadIdx.x].w = fmaxf(sm[threadIdx.x].w, o.w);
    }
    __syncthreads();
  }
  if (threadIdx.x == 0) part[blockIdx.x] = sm[0];
}

__global__ void k_elmax2(const float4* __restrict__ part, float* __restrict__ elmax) {
  __shared__ float4 sm[128];
  int t = threadIdx.x;
  sm[t] = part[t];
  __syncthreads();
  for (int off = 64; off; off >>= 1) {
    if (t < off) {
      float4 o = sm[t + off];
      sm[t].x = fmaxf(sm[t].x, o.x);
      sm[t].y = fmaxf(sm[t].y, o.y);
      sm[t].z = fmaxf(sm[t].z, o.z);
      sm[t].w = fmaxf(sm[t].w, o.w);
    }
    __syncthreads();
  }
  if (t == 0) {
    elmax[0] = sm[0].x; elmax[1] = sm[0].y;
    elmax[2] = sm[0].z; elmax[3] = sm[0].w;
  }
}

// ---------------- single-pass softmax aggregation (1 wave/node, bf16 gather) -----
// 4 independent load/accumulate chains for MLP.
__global__ __launch_bounds__(256, 8) void k_aggregate(
    const ushort* __restrict__ hf, const float* __restrict__ el,
    const float* __restrict__ er, const int* __restrict__ rowptr,
    const int* __restrict__ ssort, const float* __restrict__ bias,
    const float* __restrict__ elmax, float* __restrict__ hpre, int n, int addres) {
  int gid = blockIdx.x * 256 + threadIdx.x;
  int wid = gid >> 6, lane = gid & 63;
  if (wid >= n) return;
  int beg = rowptr[wid], end = rowptr[wid + 1];
  int h = lane >> 4;
  int c0 = 2 * lane;
  float erh = er[(size_t)4 * wid + h];
  float mu = elmax[h] + erh;
  mu = fmaxf(mu, NEG * mu);
  float s0 = 0.f, a00 = 0.f, a10 = 0.f;
  float s1 = 0.f, a01 = 0.f, a11 = 0.f;
  float s2 = 0.f, a02 = 0.f, a12 = 0.f;
  float s3 = 0.f, a03 = 0.f, a13 = 0.f;
  int cnt = end - beg;
  int j = beg;
  int rem = cnt & 3;
  for (int t = 0; t < rem; ++t, ++j) {
    int sidx = ssort[j];
    float e = el[(size_t)4 * sidx + h] + erh;
    e = fmaxf(e, NEG * e);
    float wgt = __expf(e - mu);
    unsigned hv = *(const unsigned*)(hf + (size_t)sidx * 128 + c0);
    s0 += wgt; a00 += wgt * bflo(hv); a10 += wgt * bfhi(hv);
  }
  for (; j < end; j += 4) {
    int sA = ssort[j], sB = ssort[j + 1], sC = ssort[j + 2], sD = ssort[j + 3];
    float eA = el[(size_t)4 * sA + h] + erh;
    float eB = el[(size_t)4 * sB + h] + erh;
    float eC = el[(size_t)4 * sC + h] + erh;
    float eD = el[(size_t)4 * sD + h] + erh;
    unsigned hA = *(const unsigned*)(hf + (size_t)sA * 128 + c0);
    unsigned hB = *(const unsigned*)(hf + (size_t)sB * 128 + c0);
    unsigned hC = *(const unsigned*)(hf + (size_t)sC * 128 + c0);
    unsigned hD = *(const unsigned*)(hf + (size_t)sD * 128 + c0);
    eA = fmaxf(eA, NEG * eA); eB = fmaxf(eB, NEG * eB);
    eC = fmaxf(eC, NEG * eC); eD = fmaxf(eD, NEG * eD);
    float wA = __expf(eA - mu), wB = __expf(eB - mu);
    float wC = __expf(eC - mu), wD = __expf(eD - mu);
    s0 += wA; a00 += wA * bflo(hA); a10 += wA * bfhi(hA);
    s1 += wB; a01 += wB * bflo(hB); a11 += wB * bfhi(hB);
    s2 += wC; a02 += wC * bflo(hC); a12 += wC * bfhi(hC);
    s3 += wD; a03 += wD * bflo(hD); a13 += wD * bfhi(hD);
  }
  float s = (s0 + s1) + (s2 + s3);
  float inv = (end > beg) ? 1.f / s : 0.f;
  float a0 = ((a00 + a01) + (a02 + a03)) * inv;
  float a1 = ((a10 + a11) + (a12 + a13)) * inv;
  float2 bb = *(const float2*)&bias[c0];
  float2 res = make_float2(0.f, 0.f);
  if (addres) res = *(const float2*)(hpre + (size_t)wid * 128 + c0);
  *(float2*)(hpre + (size_t)wid * 128 + c0) =
      make_float2(a0 + bb.x + res.x, a1 + bb.y + res.y);
}

// ---------------- predictor: out = bnrelu(A) @ Wp + bp (40 cols, fp32) -----------
__global__ __launch_bounds__(320) void k_pred(
    const float* __restrict__ A, const float* __restrict__ stats,
    const float* __restrict__ W, const float* __restrict__ bias,
    float* __restrict__ out, int n) {
  __shared__ float Wl[128 * 40];
  __shared__ float Xl[32 * 132];
  for (int i = threadIdx.x; i < 128 * 40; i += 320) Wl[i] = W[i];
  int cg = threadIdx.x % 10;
  int rg = threadIdx.x / 10;
  float4 bv = *(const float4*)&bias[4 * cg];
  for (int rb = blockIdx.x * 32; rb < n; rb += gridDim.x * 32) {
    __syncthreads();
    for (int idx = threadIdx.x; idx < 1024; idx += 320) {
      int r = idx >> 5, c = (idx & 31) * 4;
      float4 v = *(const float4*)&A[(size_t)(rb + r) * 128 + c];
      float4 sc = *(const float4*)&stats[c];
      float4 sh = *(const float4*)&stats[128 + c];
      v.x = fmaxf(v.x * sc.x + sh.x, 0.f);
      v.y = fmaxf(v.y * sc.y + sh.y, 0.f);
      v.z = fmaxf(v.z * sc.z + sh.z, 0.f);
      v.w = fmaxf(v.w * sc.w + sh.w, 0.f);
      *(float4*)&Xl[r * 132 + c] = v;
    }
    __syncthreads();
    float a0 = 0.f, a1 = 0.f, a2 = 0.f, a3 = 0.f;
#pragma unroll 4
    for (int k = 0; k < 128; ++k) {
      float x = Xl[rg * 132 + k];
      float4 w = *(float4*)&Wl[k * 40 + 4 * cg];
      a0 += x * w.x; a1 += x * w.y; a2 += x * w.z; a3 += x * w.w;
    }
    float4 o = make_float4(a0 + bv.x, a1 + bv.y, a2 + bv.z, a3 + bv.w);
    *(float4*)&out[(size_t)(rb + rg) * 40 + 4 * cg] = o;
  }
}

// ---------------- batchnorm stats ----------------
__global__ __launch_bounds__(256) void k_bnpart(const float* __restrict__ x,
                                                float* __restrict__ part, int n) {
  int c = threadIdx.x & 127;
  int half = threadIdx.x >> 7;
  float s = 0.f, q = 0.f;
  for (int r = blockIdx.x * 2 + half; r < n; r += gridDim.x * 2) {
    float v = x[(size_t)r * 128 + c];
    s += v; q += v * v;
  }
  __shared__ float sm[512];
  sm[threadIdx.x] = s; sm[256 + threadIdx.x] = q;
  __syncthreads();
  if (threadIdx.x < 128) {
    part[blockIdx.x * 256 + threadIdx.x] = sm[threadIdx.x] + sm[threadIdx.x + 128];
    part[blockIdx.x * 256 + 128 + threadIdx.x] =
        sm[256 + threadIdx.x] + sm[256 + threadIdx.x + 128];
  }
}

// 1024 threads: lane-coalesced partial sums over part[g][256], then LDS reduce.
__global__ __launch_bounds__(1024) void k_bnfin(
    const float* __restrict__ part, const float* __restrict__ gamma,
    const float* __restrict__ beta, float* __restrict__ stats, int g, int n) {
  __shared__ float sm[1024];
  int v = threadIdx.x & 255;  // value index: 0..127 sum, 128..255 sumsq
  int q = threadIdx.x >> 8;   // 0..3
  float acc = 0.f;
  for (int b = q; b < g; b += 4) acc += part[(size_t)b * 256 + v];
  sm[q * 256 + v] = acc;
  __syncthreads();
  if (threadIdx.x < 256)
    sm[threadIdx.x] = (sm[threadIdx.x] + sm[256 + threadIdx.x]) +
                      (sm[512 + threadIdx.x] + sm[768 + threadIdx.x]);
  __syncthreads();
  if (threadIdx.x < 128) {
    int c = threadIdx.x;
    float mean = sm[c] / n;
    float var = sm[128 + c] / n - mean * mean;
    float rstd = rsqrtf(var + BN_EPS);
    float scale = gamma[c] * rstd;
    stats[c] = scale;
    stats[128 + c] = beta[c] - mean * scale;
  }
}

extern "C" void kernel_launch(void* const* d_in, const int* in_sizes, int n_in,
                              void* d_out, int out_size, void* d_ws, size_t ws_size,
                              hipStream_t stream) {
  const float* feat   = (const float*)d_in[0];
  const int*   src    = (const int*)d_in[1];
  const int*   dst    = (const int*)d_in[2];
  const float* W_enc  = (const float*)d_in[3];
  const float* b_enc  = (const float*)d_in[4];
  const float* Ws     = (const float*)d_in[5];
  const float* a_ls   = (const float*)d_in[6];
  const float* a_rs   = (const float*)d_in[7];
  const float* biases = (const float*)d_in[8];
  const float* gammas = (const float*)d_in[9];
  const float* betas  = (const float*)d_in[10];
  const float* W_pred = (const float*)d_in[11];
  const float* b_pred = (const float*)d_in[12];
  float* out = (float*)d_out;

  char* p = (char*)d_ws;
  auto alloc = [&](size_t bytes) {
    char* q = p;
    p += (bytes + 255) & ~(size_t)255;
    return q;
  };
  ushort* h_bf  = (ushort*)alloc((size_t)N_NODES * 128 * 2);
  ushort* hf_bf = (ushort*)alloc((size_t)N_NODES * 128 * 2);
  float* hpre   = (float*)alloc((size_t)N_NODES * 128 * 4);
  float* el     = (float*)alloc((size_t)N_NODES * 4 * 4);
  float* er     = (float*)alloc((size_t)N_NODES * 4 * 4);
  float* part   = (float*)alloc((size_t)G_BN * 256 * 4);
  float* stats  = (float*)alloc(256 * 4);
  ushort* Wpack = (ushort*)alloc((size_t)4 * 2048 * 16);
  float4* elpart= (float4*)alloc(128 * 16);
  float* elmax  = (float*)alloc(4 * 4);
  int* rowptr   = (int*)alloc((size_t)(N_NODES + 1) * 4);
  int* cursor   = (int*)alloc((size_t)N_NODES * 4);
  int* bsums    = (int*)alloc(512 * 4);
  int* ssort    = (int*)alloc((size_t)N_EDGES * 4);

  // CSR build (dst-sorted)
  hipMemsetAsync(cursor, 0, (size_t)N_NODES * 4, stream);
  k_hist<<<(N_EDGES + 255) / 256, 256, 0, stream>>>(dst, cursor, N_EDGES);
  int nb = (N_NODES + 255) / 256;  // 391
  k_scan1<<<nb, 256, 0, stream>>>(cursor, rowptr, bsums, N_NODES);
  k_scan2<<<1, 512, 0, stream>>>(bsums, nb);
  k_scan3<<<nb, 256, 0, stream>>>(rowptr, bsums, cursor, N_NODES);
  k_scatter<<<(N_EDGES + 255) / 256, 256, 0, stream>>>(src, dst, cursor, ssort, N_EDGES);

  // pack weights to MFMA fragment order
  k_packW<<<32, 256, 0, stream>>>(W_enc, Ws, Wpack);

  // encoder: h = relu(feat @ W_enc + b_enc), stored bf16
  k_mgemm<0><<<3125, 256, 0, stream>>>(feat, nullptr, Wpack, b_enc, nullptr, nullptr,
                                       nullptr, nullptr, nullptr, h_bf);

  int aggblocks = (N_NODES * 64 + 255) / 256;  // 25000
  for (int L = 0; L < 3; ++L) {
    const float* al = a_ls + L * 128;
    const float* ar = a_rs + L * 128;
    const ushort* wp = Wpack + (size_t)(1 + L) * 16384;
    if (L == 0)
      k_mgemm<1><<<3125, 256, 0, stream>>>(nullptr, h_bf, wp, nullptr, nullptr, al, ar,
                                           el, er, hf_bf);
    else
      k_mgemm<2><<<3125, 256, 0, stream>>>(hpre, nullptr, wp, nullptr, stats, al, ar,
                                           el, er, hf_bf);
    k_elmax1<<<128, 256, 0, stream>>>(el, elpart, N_NODES);
    k_elmax2<<<1, 128, 0, stream>>>(elpart, elmax);
    k_aggregate<<<aggblocks, 256, 0, stream>>>(hf_bf, el, er, rowptr, ssort,
                                               biases + L * 128, elmax, hpre, N_NODES,
                                               L > 0 ? 1 : 0);
    k_bnpart<<<G_BN, 256, 0, stream>>>(hpre, part, N_NODES);
    k_bnfin<<<1, 1024, 0, stream>>>(part, gammas + L * 128, betas + L * 128, stats, G_BN,
                                    N_NODES);
  }
  // predictor uses layer-2 BN stats
  k_pred<<<1563, 320, 0, stream>>>(hpre, stats, W_pred, b_pred, out, N_NODES);
}

// Round 5
// 468.751 us; speedup vs baseline: 2.5742x; 1.4515x over previous
//
#include <hip/hip_runtime.h>

typedef __attribute__((ext_vector_type(8))) short short8;
typedef __attribute__((ext_vector_type(4))) float f32x4;

#define N_NODES 100000
#define N_EDGES 800000
#define NEG 0.2f
#define BN_EPS 1e-5f
#define G_BN 1200

__device__ __forceinline__ ushort bf16b(float f) {
  unsigned u = __float_as_uint(f);
  return (ushort)((u + 0x7FFFu + ((u >> 16) & 1u)) >> 16);
}
__device__ __forceinline__ float bflo(unsigned u) { return __uint_as_float(u << 16); }
__device__ __forceinline__ float bfhi(unsigned u) { return __uint_as_float(u & 0xFFFF0000u); }

// ---------------- CSR build (dst-sorted edge list) ----------------
__global__ void k_hist(const int* __restrict__ dst, int* __restrict__ cnt, int e) {
  int i = blockIdx.x * blockDim.x + threadIdx.x;
  if (i < e) atomicAdd(&cnt[dst[i]], 1);
}

__global__ void k_scan1(const int* __restrict__ cnt, int* __restrict__ rowptr,
                        int* __restrict__ bsums, int n) {
  __shared__ int sm[256];
  int i = blockIdx.x * 256 + threadIdx.x;
  int v = (i < n) ? cnt[i] : 0;
  sm[threadIdx.x] = v;
  __syncthreads();
  for (int off = 1; off < 256; off <<= 1) {
    int t = (threadIdx.x >= off) ? sm[threadIdx.x - off] : 0;
    __syncthreads();
    sm[threadIdx.x] += t;
    __syncthreads();
  }
  if (i < n) rowptr[i + 1] = sm[threadIdx.x];
  if (threadIdx.x == 255) bsums[blockIdx.x] = sm[255];
}

__global__ void k_scan2(int* __restrict__ bsums, int nb) {
  __shared__ int sm[512];
  int v = (threadIdx.x < nb) ? bsums[threadIdx.x] : 0;
  sm[threadIdx.x] = v;
  __syncthreads();
  for (int off = 1; off < 512; off <<= 1) {
    int t = (threadIdx.x >= off) ? sm[threadIdx.x - off] : 0;
    __syncthreads();
    sm[threadIdx.x] += t;
    __syncthreads();
  }
  if (threadIdx.x < nb) bsums[threadIdx.x] = sm[threadIdx.x] - v;  // exclusive
}

__global__ void k_scan3(int* __restrict__ rowptr, const int* __restrict__ bsums,
                        int* __restrict__ cursor, int n) {
  int i = blockIdx.x * 256 + threadIdx.x;
  if (i < n) {
    int val = rowptr[i + 1] + bsums[blockIdx.x];
    rowptr[i + 1] = val;
    if (i + 1 < n) cursor[i + 1] = val;
  }
  if (i == 0) { rowptr[0] = 0; cursor[0] = 0; }
}

__global__ void k_scatter(const int* __restrict__ src, const int* __restrict__ dst,
                          int* __restrict__ cursor, int* __restrict__ ssort, int e) {
  int i = blockIdx.x * blockDim.x + threadIdx.x;
  if (i < e) {
    int pos = atomicAdd(&cursor[dst[i]], 1);
    ssort[pos] = src[i];
  }
}

// ---------------- pack 4 weight matrices into MFMA B-fragment order (bf16) --------
__global__ void k_packW(const float* __restrict__ W_enc, const float* __restrict__ Ws,
                        ushort* __restrict__ Wp) {
  int s = blockIdx.x * 256 + threadIdx.x;  // 4 * 2048 slots
  int wi = s >> 11, s2 = s & 2047;
  int kt = s2 >> 9, nb8 = (s2 >> 6) & 7, l = s2 & 63;
  const float* Wsrc = (wi == 0) ? W_enc : Ws + (size_t)(wi - 1) * 16384;
  int n = nb8 * 16 + (l & 15);
  int k0 = kt * 32 + (l >> 4) * 8;
  unsigned pk[4];
#pragma unroll
  for (int j = 0; j < 4; ++j) {
    ushort lo = bf16b(Wsrc[(size_t)(k0 + 2 * j) * 128 + n]);
    ushort hi = bf16b(Wsrc[(size_t)(k0 + 2 * j + 1) * 128 + n]);
    pk[j] = (unsigned)lo | ((unsigned)hi << 16);
  }
  *(uint4*)&Wp[(size_t)s * 8] = make_uint4(pk[0], pk[1], pk[2], pk[3]);
}

// ---------------- MFMA GEMM: Cb(bf16) = act(A @ W), optional el/er epilogue ------
// MODE 0: encoder (A fp32, epilogue +bias relu, no el/er)
// MODE 1: layer 0 (A bf16, el/er epilogue)
// MODE 2: layer 1/2 (A fp32 with fused BN+relu, el/er epilogue)
template <int MODE>
__global__ __launch_bounds__(256) void k_mgemm(
    const float* __restrict__ Af, const ushort* __restrict__ Ab,
    const ushort* __restrict__ Wp, const float* __restrict__ bias,
    const float* __restrict__ stats, const float* __restrict__ al,
    const float* __restrict__ ar, float* __restrict__ el, float* __restrict__ er,
    ushort* __restrict__ Cb) {
  __shared__ __align__(16) ushort Al[32 * 128];
  int tid = threadIdx.x;
  int lane = tid & 63, w = tid >> 6;
  int wr = w & 1, wc = w >> 1;
  int l15 = lane & 15, l4 = lane >> 4;
  int rb = blockIdx.x * 32;

  const uint4* wp4 = (const uint4*)Wp;
  short8 bfr[4][4];
#pragma unroll
  for (int kt = 0; kt < 4; ++kt) {
#pragma unroll
    for (int nb = 0; nb < 4; ++nb) {
      uint4 t = wp4[(size_t)((kt * 8 + wc * 4 + nb) * 64 + lane)];
      bfr[kt][nb] = *(short8*)&t;
    }
  }

  // stage A tile: 32 rows x 128 cols bf16, XOR-swizzled 16B chunks
  {
    int row = tid >> 3;
    int c16 = (tid & 7) * 16;
    int kc0 = (tid & 7) * 2;
    char* base = (char*)Al + row * 256;
    if (MODE == 1) {
      const uint4* srcp = (const uint4*)(Ab + (size_t)(rb + row) * 128 + c16);
      uint4 v0 = srcp[0], v1 = srcp[1];
      *(uint4*)(base + ((kc0 ^ (row & 7)) << 4)) = v0;
      *(uint4*)(base + (((kc0 + 1) ^ (row & 7)) << 4)) = v1;
    } else {
      const float4* srcp = (const float4*)(Af + (size_t)(rb + row) * 128 + c16);
      float4 f[4];
#pragma unroll
      for (int j = 0; j < 4; ++j) f[j] = srcp[j];
      if (MODE == 2) {
#pragma unroll
        for (int j = 0; j < 4; ++j) {
          float4 sc = *(const float4*)&stats[c16 + 4 * j];
          float4 sh = *(const float4*)&stats[128 + c16 + 4 * j];
          f[j].x = fmaxf(f[j].x * sc.x + sh.x, 0.f);
          f[j].y = fmaxf(f[j].y * sc.y + sh.y, 0.f);
          f[j].z = fmaxf(f[j].z * sc.z + sh.z, 0.f);
          f[j].w = fmaxf(f[j].w * sc.w + sh.w, 0.f);
        }
      }
      unsigned pk[8];
#pragma unroll
      for (int j = 0; j < 4; ++j) {
        pk[2 * j] = (unsigned)bf16b(f[j].x) | ((unsigned)bf16b(f[j].y) << 16);
        pk[2 * j + 1] = (unsigned)bf16b(f[j].z) | ((unsigned)bf16b(f[j].w) << 16);
      }
      *(uint4*)(base + ((kc0 ^ (row & 7)) << 4)) = make_uint4(pk[0], pk[1], pk[2], pk[3]);
      *(uint4*)(base + (((kc0 + 1) ^ (row & 7)) << 4)) = make_uint4(pk[4], pk[5], pk[6], pk[7]);
    }
  }
  __syncthreads();

  f32x4 acc[4];
#pragma unroll
  for (int nb = 0; nb < 4; ++nb) acc[nb] = (f32x4){0.f, 0.f, 0.f, 0.f};
  int arow = 16 * wr + l15;
  const char* abase = (const char*)Al + arow * 256;
  int sw = arow & 7;
#pragma unroll
  for (int kt = 0; kt < 4; ++kt) {
    short8 af = *(const short8*)(abase + (((kt * 4 + l4) ^ sw) << 4));
    acc[0] = __builtin_amdgcn_mfma_f32_16x16x32_bf16(af, bfr[kt][0], acc[0], 0, 0, 0);
    acc[1] = __builtin_amdgcn_mfma_f32_16x16x32_bf16(af, bfr[kt][1], acc[1], 0, 0, 0);
    acc[2] = __builtin_amdgcn_mfma_f32_16x16x32_bf16(af, bfr[kt][2], acc[2], 0, 0, 0);
    acc[3] = __builtin_amdgcn_mfma_f32_16x16x32_bf16(af, bfr[kt][3], acc[3], 0, 0, 0);
  }

  float alv0 = 0, alv1 = 0, alv2 = 0, alv3 = 0;
  float arv0 = 0, arv1 = 0, arv2 = 0, arv3 = 0;
  float bv0 = 0, bv1 = 0, bv2 = 0, bv3 = 0;
  if (MODE != 0) {
    alv0 = al[64 * wc + l15];      arv0 = ar[64 * wc + l15];
    alv1 = al[64 * wc + 16 + l15]; arv1 = ar[64 * wc + 16 + l15];
    alv2 = al[64 * wc + 32 + l15]; arv2 = ar[64 * wc + 32 + l15];
    alv3 = al[64 * wc + 48 + l15]; arv3 = ar[64 * wc + 48 + l15];
  } else {
    bv0 = bias[64 * wc + l15];      bv1 = bias[64 * wc + 16 + l15];
    bv2 = bias[64 * wc + 32 + l15]; bv3 = bias[64 * wc + 48 + l15];
  }
  int row0 = rb + 16 * wr + 4 * l4;
#pragma unroll
  for (int i = 0; i < 4; ++i) {
    int row = row0 + i;
    if (MODE != 0) {
      float pl0 = acc[0][i] * alv0 + acc[1][i] * alv1;
      float pr0 = acc[0][i] * arv0 + acc[1][i] * arv1;
      float pl1 = acc[2][i] * alv2 + acc[3][i] * alv3;
      float pr1 = acc[2][i] * arv2 + acc[3][i] * arv3;
#pragma unroll
      for (int o = 1; o < 16; o <<= 1) {
        pl0 += __shfl_xor(pl0, o); pr0 += __shfl_xor(pr0, o);
        pl1 += __shfl_xor(pl1, o); pr1 += __shfl_xor(pr1, o);
      }
      if (l15 == 0) {
        el[(size_t)row * 4 + 2 * wc] = pl0;     er[(size_t)row * 4 + 2 * wc] = pr0;
        el[(size_t)row * 4 + 2 * wc + 1] = pl1; er[(size_t)row * 4 + 2 * wc + 1] = pr1;
      }
    }
    float v0 = acc[0][i], v1 = acc[1][i], v2 = acc[2][i], v3 = acc[3][i];
    if (MODE == 0) {
      v0 = fmaxf(v0 + bv0, 0.f); v1 = fmaxf(v1 + bv1, 0.f);
      v2 = fmaxf(v2 + bv2, 0.f); v3 = fmaxf(v3 + bv3, 0.f);
    }
    size_t rbase = (size_t)row * 128 + 64 * wc + l15;
    Cb[rbase] = bf16b(v0);
    Cb[rbase + 16] = bf16b(v1);
    Cb[rbase + 32] = bf16b(v2);
    Cb[rbase + 48] = bf16b(v3);
  }
}

// ---------------- global per-head max of el (softmax upper bound) ----------------
__global__ __launch_bounds__(256) void k_elmax1(const float* __restrict__ el,
                                                float4* __restrict__ part, int n) {
  int gid = blockIdx.x * 256 + threadIdx.x;
  float4 m = make_float4(-1e30f, -1e30f, -1e30f, -1e30f);
  for (int i = gid; i < n; i += 128 * 256) {
    float4 v = *(const float4*)&el[(size_t)4 * i];
    m.x = fmaxf(m.x, v.x); m.y = fmaxf(m.y, v.y);
    m.z = fmaxf(m.z, v.z); m.w = fmaxf(m.w, v.w);
  }
  __shared__ float4 sm[256];
  sm[threadIdx.x] = m;
  __syncthreads();
  for (int off = 128; off; off >>= 1) {
    if (threadIdx.x < off) {
      float4 o = sm[threadIdx.x + off];
      sm[threadIdx.x].x = fmaxf(sm[threadIdx.x].x, o.x);
      sm[threadIdx.x].y = fmaxf(sm[threadIdx.x].y, o.y);
      sm[threadIdx.x].z = fmaxf(sm[threadIdx.x].z, o.z);
      sm[threadIdx.x].w = fmaxf(sm[threadIdx.x].w, o.w);
    }
    __syncthreads();
  }
  if (threadIdx.x == 0) part[blockIdx.x] = sm[0];
}

__global__ void k_elmax2(const float4* __restrict__ part, float* __restrict__ elmax) {
  __shared__ float4 sm[128];
  int t = threadIdx.x;
  sm[t] = part[t];
  __syncthreads();
  for (int off = 64; off; off >>= 1) {
    if (t < off) {
      float4 o = sm[t + off];
      sm[t].x = fmaxf(sm[t].x, o.x);
      sm[t].y = fmaxf(sm[t].y, o.y);
      sm[t].z = fmaxf(sm[t].z, o.z);
      sm[t].w = fmaxf(sm[t].w, o.w);
    }
    __syncthreads();
  }
  if (t == 0) {
    elmax[0] = sm[0].x; elmax[1] = sm[0].y;
    elmax[2] = sm[0].z; elmax[3] = sm[0].w;
  }
}

// ---------------- single-pass softmax aggregation (1 wave/node, bf16 gather) -----
// 4 independent load/accumulate chains for MLP.
__global__ __launch_bounds__(256, 8) void k_aggregate(
    const ushort* __restrict__ hf, const float* __restrict__ el,
    const float* __restrict__ er, const int* __restrict__ rowptr,
    const int* __restrict__ ssort, const float* __restrict__ bias,
    const float* __restrict__ elmax, float* __restrict__ hpre, int n, int addres) {
  int gid = blockIdx.x * 256 + threadIdx.x;
  int wid = gid >> 6, lane = gid & 63;
  if (wid >= n) return;
  int beg = rowptr[wid], end = rowptr[wid + 1];
  int h = lane >> 4;
  int c0 = 2 * lane;
  float erh = er[(size_t)4 * wid + h];
  float mu = elmax[h] + erh;
  mu = fmaxf(mu, NEG * mu);
  float s0 = 0.f, a00 = 0.f, a10 = 0.f;
  float s1 = 0.f, a01 = 0.f, a11 = 0.f;
  float s2 = 0.f, a02 = 0.f, a12 = 0.f;
  float s3 = 0.f, a03 = 0.f, a13 = 0.f;
  int cnt = end - beg;
  int j = beg;
  int rem = cnt & 3;
  for (int t = 0; t < rem; ++t, ++j) {
    int sidx = ssort[j];
    float e = el[(size_t)4 * sidx + h] + erh;
    e = fmaxf(e, NEG * e);
    float wgt = __expf(e - mu);
    unsigned hv = *(const unsigned*)(hf + (size_t)sidx * 128 + c0);
    s0 += wgt; a00 += wgt * bflo(hv); a10 += wgt * bfhi(hv);
  }
  for (; j < end; j += 4) {
    int sA = ssort[j], sB = ssort[j + 1], sC = ssort[j + 2], sD = ssort[j + 3];
    float eA = el[(size_t)4 * sA + h] + erh;
    float eB = el[(size_t)4 * sB + h] + erh;
    float eC = el[(size_t)4 * sC + h] + erh;
    float eD = el[(size_t)4 * sD + h] + erh;
    unsigned hA = *(const unsigned*)(hf + (size_t)sA * 128 + c0);
    unsigned hB = *(const unsigned*)(hf + (size_t)sB * 128 + c0);
    unsigned hC = *(const unsigned*)(hf + (size_t)sC * 128 + c0);
    unsigned hD = *(const unsigned*)(hf + (size_t)sD * 128 + c0);
    eA = fmaxf(eA, NEG * eA); eB = fmaxf(eB, NEG * eB);
    eC = fmaxf(eC, NEG * eC); eD = fmaxf(eD, NEG * eD);
    float wA = __expf(eA - mu), wB = __expf(eB - mu);
    float wC = __expf(eC - mu), wD = __expf(eD - mu);
    s0 += wA; a00 += wA * bflo(hA); a10 += wA * bfhi(hA);
    s1 += wB; a01 += wB * bflo(hB); a11 += wB * bfhi(hB);
    s2 += wC; a02 += wC * bflo(hC); a12 += wC * bfhi(hC);
    s3 += wD; a03 += wD * bflo(hD); a13 += wD * bfhi(hD);
  }
  float s = (s0 + s1) + (s2 + s3);
  float inv = (end > beg) ? 1.f / s : 0.f;
  float a0 = ((a00 + a01) + (a02 + a03)) * inv;
  float a1 = ((a10 + a11) + (a12 + a13)) * inv;
  float2 bb = *(const float2*)&bias[c0];
  float2 res = make_float2(0.f, 0.f);
  if (addres) res = *(const float2*)(hpre + (size_t)wid * 128 + c0);
  *(float2*)(hpre + (size_t)wid * 128 + c0) =
      make_float2(a0 + bb.x + res.x, a1 + bb.y + res.y);
}

// ---------------- predictor: out = bnrelu(A) @ Wp + bp (40 cols, fp32) -----------
__global__ __launch_bounds__(320) void k_pred(
    const float* __restrict__ A, const float* __restrict__ stats,
    const float* __restrict__ W, const float* __restrict__ bias,
    float* __restrict__ out, int n) {
  __shared__ float Wl[128 * 40];
  __shared__ float Xl[32 * 132];
  for (int i = threadIdx.x; i < 128 * 40; i += 320) Wl[i] = W[i];
  int cg = threadIdx.x % 10;
  int rg = threadIdx.x / 10;
  float4 bv = *(const float4*)&bias[4 * cg];
  for (int rb = blockIdx.x * 32; rb < n; rb += gridDim.x * 32) {
    __syncthreads();
    for (int idx = threadIdx.x; idx < 1024; idx += 320) {
      int r = idx >> 5, c = (idx & 31) * 4;
      float4 v = *(const float4*)&A[(size_t)(rb + r) * 128 + c];
      float4 sc = *(const float4*)&stats[c];
      float4 sh = *(const float4*)&stats[128 + c];
      v.x = fmaxf(v.x * sc.x + sh.x, 0.f);
      v.y = fmaxf(v.y * sc.y + sh.y, 0.f);
      v.z = fmaxf(v.z * sc.z + sh.z, 0.f);
      v.w = fmaxf(v.w * sc.w + sh.w, 0.f);
      *(float4*)&Xl[r * 132 + c] = v;
    }
    __syncthreads();
    float a0 = 0.f, a1 = 0.f, a2 = 0.f, a3 = 0.f;
#pragma unroll 4
    for (int k = 0; k < 128; ++k) {
      float x = Xl[rg * 132 + k];
      float4 w = *(float4*)&Wl[k * 40 + 4 * cg];
      a0 += x * w.x; a1 += x * w.y; a2 += x * w.z; a3 += x * w.w;
    }
    float4 o = make_float4(a0 + bv.x, a1 + bv.y, a2 + bv.z, a3 + bv.w);
    *(float4*)&out[(size_t)(rb + rg) * 40 + 4 * cg] = o;
  }
}

// ---------------- batchnorm stats ----------------
__global__ __launch_bounds__(256) void k_bnpart(const float* __restrict__ x,
                                                float* __restrict__ part, int n) {
  int c = threadIdx.x & 127;
  int half = threadIdx.x >> 7;
  float s = 0.f, q = 0.f;
  for (int r = blockIdx.x * 2 + half; r < n; r += gridDim.x * 2) {
    float v = x[(size_t)r * 128 + c];
    s += v; q += v * v;
  }
  __shared__ float sm[512];
  sm[threadIdx.x] = s; sm[256 + threadIdx.x] = q;
  __syncthreads();
  if (threadIdx.x < 128) {
    part[blockIdx.x * 256 + threadIdx.x] = sm[threadIdx.x] + sm[threadIdx.x + 128];
    part[blockIdx.x * 256 + 128 + threadIdx.x] =
        sm[256 + threadIdx.x] + sm[256 + threadIdx.x + 128];
  }
}

// parallel column reduce: block v sums part[b*256+v] over b -> colsum[v]
__global__ __launch_bounds__(256) void k_bnred(const float* __restrict__ part,
                                               float* __restrict__ colsum, int g) {
  int v = blockIdx.x;  // 0..255
  float acc = 0.f;
  for (int b = threadIdx.x; b < g; b += 256) acc += part[(size_t)b * 256 + v];
  __shared__ float sm[256];
  sm[threadIdx.x] = acc;
  __syncthreads();
  for (int off = 128; off; off >>= 1) {
    if (threadIdx.x < off) sm[threadIdx.x] += sm[threadIdx.x + off];
    __syncthreads();
  }
  if (threadIdx.x == 0) colsum[v] = sm[0];
}

__global__ void k_bnstat(const float* __restrict__ colsum, const float* __restrict__ gamma,
                         const float* __restrict__ beta, float* __restrict__ stats, int n) {
  int c = threadIdx.x;  // 128 threads
  float mean = colsum[c] / n;
  float var = colsum[128 + c] / n - mean * mean;
  float rstd = rsqrtf(var + BN_EPS);
  float scale = gamma[c] * rstd;
  stats[c] = scale;
  stats[128 + c] = beta[c] - mean * scale;
}

extern "C" void kernel_launch(void* const* d_in, const int* in_sizes, int n_in,
                              void* d_out, int out_size, void* d_ws, size_t ws_size,
                              hipStream_t stream) {
  const float* feat   = (const float*)d_in[0];
  const int*   src    = (const int*)d_in[1];
  const int*   dst    = (const int*)d_in[2];
  const float* W_enc  = (const float*)d_in[3];
  const float* b_enc  = (const float*)d_in[4];
  const float* Ws     = (const float*)d_in[5];
  const float* a_ls   = (const float*)d_in[6];
  const float* a_rs   = (const float*)d_in[7];
  const float* biases = (const float*)d_in[8];
  const float* gammas = (const float*)d_in[9];
  const float* betas  = (const float*)d_in[10];
  const float* W_pred = (const float*)d_in[11];
  const float* b_pred = (const float*)d_in[12];
  float* out = (float*)d_out;

  char* p = (char*)d_ws;
  auto alloc = [&](size_t bytes) {
    char* q = p;
    p += (bytes + 255) & ~(size_t)255;
    return q;
  };
  ushort* h_bf  = (ushort*)alloc((size_t)N_NODES * 128 * 2);
  ushort* hf_bf = (ushort*)alloc((size_t)N_NODES * 128 * 2);
  float* hpre   = (float*)alloc((size_t)N_NODES * 128 * 4);
  float* el     = (float*)alloc((size_t)N_NODES * 4 * 4);
  float* er     = (float*)alloc((size_t)N_NODES * 4 * 4);
  float* part   = (float*)alloc((size_t)G_BN * 256 * 4);
  float* colsum = (float*)alloc(256 * 4);
  float* stats  = (float*)alloc(256 * 4);
  ushort* Wpack = (ushort*)alloc((size_t)4 * 2048 * 16);
  float4* elpart= (float4*)alloc(128 * 16);
  float* elmax  = (float*)alloc(4 * 4);
  int* rowptr   = (int*)alloc((size_t)(N_NODES + 1) * 4);
  int* cursor   = (int*)alloc((size_t)N_NODES * 4);
  int* bsums    = (int*)alloc(512 * 4);
  int* ssort    = (int*)alloc((size_t)N_EDGES * 4);

  // CSR build (dst-sorted)
  hipMemsetAsync(cursor, 0, (size_t)N_NODES * 4, stream);
  k_hist<<<(N_EDGES + 255) / 256, 256, 0, stream>>>(dst, cursor, N_EDGES);
  int nb = (N_NODES + 255) / 256;  // 391
  k_scan1<<<nb, 256, 0, stream>>>(cursor, rowptr, bsums, N_NODES);
  k_scan2<<<1, 512, 0, stream>>>(bsums, nb);
  k_scan3<<<nb, 256, 0, stream>>>(rowptr, bsums, cursor, N_NODES);
  k_scatter<<<(N_EDGES + 255) / 256, 256, 0, stream>>>(src, dst, cursor, ssort, N_EDGES);

  // pack weights to MFMA fragment order
  k_packW<<<32, 256, 0, stream>>>(W_enc, Ws, Wpack);

  // encoder: h = relu(feat @ W_enc + b_enc), stored bf16
  k_mgemm<0><<<3125, 256, 0, stream>>>(feat, nullptr, Wpack, b_enc, nullptr, nullptr,
                                       nullptr, nullptr, nullptr, h_bf);

  int aggblocks = (N_NODES * 64 + 255) / 256;  // 25000
  for (int L = 0; L < 3; ++L) {
    const float* al = a_ls + L * 128;
    const float* ar = a_rs + L * 128;
    const ushort* wp = Wpack + (size_t)(1 + L) * 16384;
    if (L == 0)
      k_mgemm<1><<<3125, 256, 0, stream>>>(nullptr, h_bf, wp, nullptr, nullptr, al, ar,
                                           el, er, hf_bf);
    else
      k_mgemm<2><<<3125, 256, 0, stream>>>(hpre, nullptr, wp, nullptr, stats, al, ar,
                                           el, er, hf_bf);
    k_elmax1<<<128, 256, 0, stream>>>(el, elpart, N_NODES);
    k_elmax2<<<1, 128, 0, stream>>>(elpart, elmax);
    k_aggregate<<<aggblocks, 256, 0, stream>>>(hf_bf, el, er, rowptr, ssort,
                                               biases + L * 128, elmax, hpre, N_NODES,
                                               L > 0 ? 1 : 0);
    k_bnpart<<<G_BN, 256, 0, stream>>>(hpre, part, N_NODES);
    k_bnred<<<256, 256, 0, stream>>>(part, colsum, G_BN);
    k_bnstat<<<1, 128, 0, stream>>>(colsum, gammas + L * 128, betas + L * 128, stats,
                                    N_NODES);
  }
  // predictor uses layer-2 BN stats
  k_pred<<<1563, 320, 0, stream>>>(hpre, stats, W_pred, b_pred, out, N_NODES);
}